// Round 1
// baseline (1199.630 us; speedup 1.0000x reference)
//
#include <hip/hip_runtime.h>

#define BB 2
#define SS 2048
#define DD 1024
#define HH 16
#define HD 64
#define MM (BB*SS)   // 4096

__device__ __forceinline__ float dot4f(float4 a, float4 b){
  return a.x*b.x + a.y*b.y + a.z*b.z + a.w*b.w;
}

// ---------------------------------------------------------------------------
// Kernel 1: wv[i][d] = dot(W_i[d,:], dWv[i,:]);  cv[i] = dot(b_i, dWv[i]) + dbv[i]
// grid (DD+1, 4), block 256
__global__ void precompute_kernel(const float* __restrict__ Wq_, const float* __restrict__ bq_,
                                  const float* __restrict__ Wk_, const float* __restrict__ bk_,
                                  const float* __restrict__ Wv_, const float* __restrict__ bv_,
                                  const float* __restrict__ Wo_, const float* __restrict__ bo_,
                                  const float* __restrict__ dWv, const float* __restrict__ dbv,
                                  float* __restrict__ wv, float* __restrict__ cv) {
  int i = blockIdx.y;
  const float* W    = (i==0)?Wq_:(i==1)?Wk_:(i==2)?Wv_:Wo_;
  const float* bvec = (i==0)?bq_:(i==1)?bk_:(i==2)?bv_:bo_;
  const float* s = dWv + i*DD;
  int t = threadIdx.x;
  __shared__ float red[256];
  float acc = 0.f;
  if (blockIdx.x < DD) {
    const float* row = W + (size_t)blockIdx.x * DD;
    for (int e = t; e < DD; e += 256) acc += row[e]*s[e];
  } else {
    for (int e = t; e < DD; e += 256) acc += bvec[e]*s[e];
  }
  red[t] = acc; __syncthreads();
  for (int off=128; off>0; off>>=1){ if(t<off) red[t]+=red[t+off]; __syncthreads(); }
  if (t==0) {
    if (blockIdx.x < DD) wv[i*DD + blockIdx.x] = red[0];
    else                 cv[i] = red[0] + dbv[i];
  }
}

// ---------------------------------------------------------------------------
// Kernel 2: kraw[i] = x @ dWk[i]   (M=4096, K=1024, N=1024), fp32 tiled
// grid (8, 32, 4), block 256. 128x128 tile, BK=16, 8x8 per thread (split halves).
__global__ __launch_bounds__(256) void gemm_dwk_kernel(const float* __restrict__ x,
                          const float* __restrict__ dWk, float* __restrict__ kraw) {
  int i = blockIdx.z;
  const float* Bmat = dWk + (size_t)i*DD*DD;
  float* C = kraw + (size_t)i*MM*DD;
  int n0 = blockIdx.x * 128;
  int m0 = blockIdx.y * 128;
  int t  = threadIdx.x;
  int tx = t & 15, ty = t >> 4;
  __shared__ float As[16][132];   // [k][m], pad 132 (mult of 4, !=0 mod 32)
  __shared__ float Bs[16][132];   // [k][n]
  float acc[2][2][4][4] = {};     // [mh][nh][mi][nj]
  for (int k0 = 0; k0 < DD; k0 += 16) {
    __syncthreads();
    #pragma unroll
    for (int ii = 0; ii < 2; ii++) {
      int f4 = t + ii*256;            // 0..511
      int m  = f4 >> 2;               // 0..127
      int kq = f4 & 3;                // 0..3
      float4 av = *(const float4*)(x + (size_t)(m0+m)*DD + k0 + kq*4);
      As[kq*4+0][m] = av.x; As[kq*4+1][m] = av.y;
      As[kq*4+2][m] = av.z; As[kq*4+3][m] = av.w;
      int kk = f4 >> 5;               // 0..15
      int nc = f4 & 31;               // 0..31
      *(float4*)(&Bs[kk][nc*4]) = *(const float4*)(Bmat + (size_t)(k0+kk)*DD + n0 + nc*4);
    }
    __syncthreads();
    #pragma unroll
    for (int kk = 0; kk < 16; kk++) {
      float4 a0 = *(const float4*)(&As[kk][ty*4]);
      float4 a1 = *(const float4*)(&As[kk][ty*4+64]);
      float4 b0 = *(const float4*)(&Bs[kk][tx*4]);
      float4 b1 = *(const float4*)(&Bs[kk][tx*4+64]);
      float am[2][4] = {{a0.x,a0.y,a0.z,a0.w},{a1.x,a1.y,a1.z,a1.w}};
      float bn[2][4] = {{b0.x,b0.y,b0.z,b0.w},{b1.x,b1.y,b1.z,b1.w}};
      #pragma unroll
      for (int mh=0; mh<2; mh++)
      #pragma unroll
      for (int nh=0; nh<2; nh++)
      #pragma unroll
      for (int mi=0; mi<4; mi++)
      #pragma unroll
      for (int nj=0; nj<4; nj++)
        acc[mh][nh][mi][nj] += am[mh][mi]*bn[nh][nj];
    }
  }
  #pragma unroll
  for (int mh=0; mh<2; mh++)
  #pragma unroll
  for (int mi=0; mi<4; mi++) {
    int m = m0 + ty*4 + mi + mh*64;
    #pragma unroll
    for (int nh=0; nh<2; nh++) {
      float4 v4 = make_float4(acc[mh][nh][mi][0], acc[mh][nh][mi][1],
                              acc[mh][nh][mi][2], acc[mh][nh][mi][3]);
      *(float4*)(C + (size_t)m*DD + n0 + tx*4 + nh*64) = v4;
    }
  }
}

// ---------------------------------------------------------------------------
// Kernel 3: delta transform i=0..2, in-place on kraw_i row -> q/k/v
// grid (MM, 3), block 256
__global__ void delta_qkv_kernel(const float* __restrict__ x, float* __restrict__ kraw,
                                 const float* __restrict__ dbw, const float* __restrict__ dbb,
                                 const float* __restrict__ wv, const float* __restrict__ cv) {
  int m = blockIdx.x;
  int i = blockIdx.y;
  int t = threadIdx.x;
  const float* xr = x + (size_t)m*DD;
  float* kr = kraw + (size_t)i*MM*DD + (size_t)m*DD;
  float4 xv  = *(const float4*)(xr + t*4);
  float4 kv  = *(const float4*)(kr + t*4);
  float4 bwv = *(const float4*)(dbw + i*DD + t*4);
  float4 wvv = *(const float4*)(wv  + i*DD + t*4);
  __shared__ float4 red[256];
  red[t] = make_float4(dot4f(kv,kv), dot4f(kv,xv), dot4f(xv,bwv), dot4f(xv,wvv));
  __syncthreads();
  for (int off=128; off>0; off>>=1){
    if (t<off){ red[t].x+=red[t+off].x; red[t].y+=red[t+off].y;
                red[t].z+=red[t+off].z; red[t].w+=red[t+off].w; }
    __syncthreads();
  }
  __shared__ float coef_s;
  if (t==0) {
    float nrmE = sqrtf(red[0].x) + 1e-8f;
    float kdh  = red[0].y / nrmE;
    float beta = 2.f / (1.f + expf(-(red[0].z + dbb[i])));
    float vs   = red[0].w + cv[i];
    coef_s = beta * (vs - kdh) / nrmE;
  }
  __syncthreads();
  float c = coef_s;
  float4 o;
  o.x = xv.x + c*kv.x; o.y = xv.y + c*kv.y;
  o.z = xv.z + c*kv.z; o.w = xv.w + c*kv.w;
  *(float4*)(kr + t*4) = o;
}

// ---------------------------------------------------------------------------
// Kernel 4: flash attention fp32. grid (SS/64, HH, BB), block 256.
// Per block: 64 q-rows x full head. Register-tiled 4x4 QK^T and PV.
__global__ __launch_bounds__(256) void flash_kernel(const float* __restrict__ q,
    const float* __restrict__ k, const float* __restrict__ v, float* __restrict__ o) {
  int b = blockIdx.z, h = blockIdx.y, qt = blockIdx.x;
  int t = threadIdx.x;
  int tx = t & 15, ty = t >> 4;
  __shared__ float qT[64*64];    // [d][r]
  __shared__ float vS[64*64];    // [j][c]
  __shared__ float kp[68*64];    // scores: kT[d][j] stride 64 ; P: pT[j][r] stride 68
  const size_t hoff = (size_t)h*HD;
  #pragma unroll
  for (int ii=0; ii<4; ii++) {
    int f4 = t + ii*256;   // 0..1023
    int r  = f4 >> 4;      // 0..63
    int dc = f4 & 15;      // 0..15
    float4 qv = *(const float4*)(q + (size_t)(b*SS + qt*64 + r)*DD + hoff + dc*4);
    qT[(dc*4+0)*64 + r] = qv.x; qT[(dc*4+1)*64 + r] = qv.y;
    qT[(dc*4+2)*64 + r] = qv.z; qT[(dc*4+3)*64 + r] = qv.w;
  }
  float m_i[4], l_i[4], oacc[4][4];
  #pragma unroll
  for (int a=0;a<4;a++){ m_i[a]=-1e30f; l_i[a]=0.f;
    #pragma unroll
    for (int c=0;c<4;c++) oacc[a][c]=0.f; }

  for (int kt = 0; kt < SS/64; kt++) {
    __syncthreads();   // prev PV done reading vS/kp
    #pragma unroll
    for (int ii=0; ii<4; ii++) {
      int f4 = t + ii*256;
      int r  = f4 >> 4;
      int dc = f4 & 15;
      size_t grow = (size_t)(b*SS + kt*64 + r)*DD + hoff + dc*4;
      float4 kv4 = *(const float4*)(k + grow);
      kp[(dc*4+0)*64 + r] = kv4.x; kp[(dc*4+1)*64 + r] = kv4.y;
      kp[(dc*4+2)*64 + r] = kv4.z; kp[(dc*4+3)*64 + r] = kv4.w;
      *(float4*)(&vS[r*64 + dc*4]) = *(const float4*)(v + grow);
    }
    __syncthreads();
    // scores s[i][j] = q_row(ty*4+i) . k_row(tx*4+j)
    float s[4][4];
    #pragma unroll
    for (int a=0;a<4;a++)
      #pragma unroll
      for (int c=0;c<4;c++) s[a][c]=0.f;
    #pragma unroll 16
    for (int d=0; d<64; d++) {
      float4 q4 = *(const float4*)(&qT[d*64 + ty*4]);
      float4 k4 = *(const float4*)(&kp[d*64 + tx*4]);
      float qa[4] = {q4.x,q4.y,q4.z,q4.w};
      float ka[4] = {k4.x,k4.y,k4.z,k4.w};
      #pragma unroll
      for (int a=0;a<4;a++)
        #pragma unroll
        for (int c=0;c<4;c++) s[a][c] += qa[a]*ka[c];
    }
    #pragma unroll
    for (int a=0;a<4;a++)
      #pragma unroll
      for (int c=0;c<4;c++) s[a][c] *= 0.125f;
    // online softmax (row group = 16 lanes, same ty)
    float p[4][4], alpha[4];
    #pragma unroll
    for (int a=0;a<4;a++) {
      float mx = fmaxf(fmaxf(s[a][0],s[a][1]), fmaxf(s[a][2],s[a][3]));
      #pragma unroll
      for (int off=1; off<16; off<<=1) mx = fmaxf(mx, __shfl_xor(mx, off));
      float mn = fmaxf(m_i[a], mx);
      alpha[a] = expf(m_i[a] - mn);
      m_i[a] = mn;
      #pragma unroll
      for (int c=0;c<4;c++) p[a][c] = expf(s[a][c] - mn);
      float sm = p[a][0]+p[a][1]+p[a][2]+p[a][3];
      #pragma unroll
      for (int off=1; off<16; off<<=1) sm += __shfl_xor(sm, off);
      l_i[a] = l_i[a]*alpha[a] + sm;
      #pragma unroll
      for (int c=0;c<4;c++) oacc[a][c] *= alpha[a];
    }
    __syncthreads();   // all kT reads done -> reuse kp for P
    #pragma unroll
    for (int jj=0;jj<4;jj++){
      float4 pv = make_float4(p[0][jj],p[1][jj],p[2][jj],p[3][jj]);
      *(float4*)(&kp[(tx*4+jj)*68 + ty*4]) = pv;   // pT[j][r], stride 68 (16B aligned)
    }
    __syncthreads();
    // PV: oacc[a][c] += sum_j P[row a][j] * V[j][col c]
    #pragma unroll 16
    for (int j=0;j<64;j++){
      float4 p4 = *(const float4*)(&kp[j*68 + ty*4]);
      float4 v4 = *(const float4*)(&vS[j*64 + tx*4]);
      float pa[4] = {p4.x,p4.y,p4.z,p4.w};
      float va[4] = {v4.x,v4.y,v4.z,v4.w};
      #pragma unroll
      for (int a=0;a<4;a++)
        #pragma unroll
        for (int c=0;c<4;c++) oacc[a][c] += pa[a]*va[c];
    }
  }
  #pragma unroll
  for (int a=0;a<4;a++){
    float inv = 1.f/l_i[a];
    float4 ov = make_float4(oacc[a][0]*inv, oacc[a][1]*inv, oacc[a][2]*inv, oacc[a][3]*inv);
    *(float4*)(o + (size_t)(b*SS + qt*64 + ty*4 + a)*DD + hoff + tx*4) = ov;
  }
}

// ---------------------------------------------------------------------------
// Kernel 5: delta #3 (v3 from attn.wv3) + LayerNorm, fused. grid MM, block 256.
__global__ void final_kernel(const float* __restrict__ x, const float* __restrict__ kraw3,
                             const float* __restrict__ attn,
                             const float* __restrict__ dbw, const float* __restrict__ dbb,
                             const float* __restrict__ wv, const float* __restrict__ cv,
                             const float* __restrict__ ln_g, const float* __restrict__ ln_b,
                             float* __restrict__ out) {
  int m = blockIdx.x; int t = threadIdx.x;
  const float* xr = x     + (size_t)m*DD;
  const float* kr = kraw3 + (size_t)m*DD;
  const float* ar = attn  + (size_t)m*DD;
  float4 xv  = *(const float4*)(xr + t*4);
  float4 kv  = *(const float4*)(kr + t*4);
  float4 av  = *(const float4*)(ar + t*4);
  float4 bwv = *(const float4*)(dbw + 3*DD + t*4);
  float4 wvv = *(const float4*)(wv  + 3*DD + t*4);
  __shared__ float4 red[256];
  red[t] = make_float4(dot4f(kv,kv), dot4f(kv,xv), dot4f(xv,bwv), dot4f(av,wvv));
  __syncthreads();
  for (int off=128; off>0; off>>=1){
    if (t<off){ red[t].x+=red[t+off].x; red[t].y+=red[t+off].y;
                red[t].z+=red[t+off].z; red[t].w+=red[t+off].w; }
    __syncthreads();
  }
  __shared__ float coef_s;
  if (t==0) {
    float nrmE = sqrtf(red[0].x) + 1e-8f;
    float kdh  = red[0].y / nrmE;
    float beta = 2.f / (1.f + expf(-(red[0].z + dbb[3])));
    float v3   = red[0].w + cv[3];
    coef_s = beta * (v3 - kdh) / nrmE;
  }
  __syncthreads();
  float c = coef_s;
  float y0 = xv.x + c*kv.x, y1 = xv.y + c*kv.y, y2 = xv.z + c*kv.z, y3 = xv.w + c*kv.w;
  // LayerNorm reductions
  red[t] = make_float4(y0+y1+y2+y3, y0*y0+y1*y1+y2*y2+y3*y3, 0.f, 0.f);
  __syncthreads();
  for (int off=128; off>0; off>>=1){
    if (t<off){ red[t].x+=red[t+off].x; red[t].y+=red[t+off].y; }
    __syncthreads();
  }
  __shared__ float2 stats_s;
  if (t==0) {
    float mu  = red[0].x * (1.f/DD);
    float var = red[0].y * (1.f/DD) - mu*mu;
    stats_s = make_float2(mu, rsqrtf(var + 1e-5f));
  }
  __syncthreads();
  float mu = stats_s.x, rstd = stats_s.y;
  float4 g = *(const float4*)(ln_g + t*4);
  float4 bb = *(const float4*)(ln_b + t*4);
  float4 ov;
  ov.x = (y0-mu)*rstd*g.x + bb.x;
  ov.y = (y1-mu)*rstd*g.y + bb.y;
  ov.z = (y2-mu)*rstd*g.z + bb.z;
  ov.w = (y3-mu)*rstd*g.w + bb.w;
  *(float4*)(out + (size_t)m*DD + t*4) = ov;
}

// ---------------------------------------------------------------------------
extern "C" void kernel_launch(void* const* d_in, const int* in_sizes, int n_in,
                              void* d_out, int out_size, void* d_ws, size_t ws_size,
                              hipStream_t stream) {
  const float* x    = (const float*)d_in[0];
  const float* Wq_  = (const float*)d_in[1];
  const float* bq_  = (const float*)d_in[2];
  const float* Wk_  = (const float*)d_in[3];
  const float* bk_  = (const float*)d_in[4];
  const float* Wv_  = (const float*)d_in[5];
  const float* bv_  = (const float*)d_in[6];
  const float* Wo_  = (const float*)d_in[7];
  const float* bo_  = (const float*)d_in[8];
  const float* dWk  = (const float*)d_in[9];
  const float* dbw  = (const float*)d_in[10];
  const float* dbb  = (const float*)d_in[11];
  const float* dWv  = (const float*)d_in[12];
  const float* dbv  = (const float*)d_in[13];
  const float* ln_g = (const float*)d_in[14];
  const float* ln_b = (const float*)d_in[15];
  float* out = (float*)d_out;
  float* WS  = (float*)d_ws;

  float* wv   = WS;                 // 4*1024
  float* cv   = WS + 4096;          // 4
  float* kraw = WS + 8192;          // 4 * M * D
  float* attn = WS + 8192 + 4*(size_t)MM*DD;  // M * D

  precompute_kernel<<<dim3(DD+1, 4), 256, 0, stream>>>(Wq_,bq_,Wk_,bk_,Wv_,bv_,Wo_,bo_,dWv,dbv,wv,cv);
  gemm_dwk_kernel<<<dim3(8, 32, 4), 256, 0, stream>>>(x, dWk, kraw);
  delta_qkv_kernel<<<dim3(MM, 3), 256, 0, stream>>>(x, kraw, dbw, dbb, wv, cv);
  flash_kernel<<<dim3(SS/64, HH, BB), 256, 0, stream>>>(
      kraw /*q*/, kraw + (size_t)MM*DD /*k*/, kraw + 2*(size_t)MM*DD /*v*/, attn);
  final_kernel<<<MM, 256, 0, stream>>>(x, kraw + 3*(size_t)MM*DD, attn,
                                       dbw, dbb, wv, cv, ln_g, ln_b, out);
}

// Round 2
// 290.022 us; speedup vs baseline: 4.1363x; 4.1363x over previous
//
#include <hip/hip_runtime.h>

#define BB 2
#define SS 2048
#define DD 1024
#define HH 16
#define HD 64
#define MM (BB*SS)   // 4096

typedef unsigned short u16;
typedef __attribute__((ext_vector_type(8))) short bf16x8;
typedef __attribute__((ext_vector_type(4))) float f32x4;

__device__ __forceinline__ u16 f2bf(float f){
  unsigned u = __float_as_uint(f);
  u += 0x7FFF + ((u >> 16) & 1);      // round-to-nearest-even
  return (u16)(u >> 16);
}
__device__ __forceinline__ float bf2f(u16 h){
  return __uint_as_float(((unsigned)h) << 16);
}
__device__ __forceinline__ float dot4f(float4 a, float4 b){
  return a.x*b.x + a.y*b.y + a.z*b.z + a.w*b.w;
}

// ---------------------------------------------------------------------------
// Kernel 1: wv[i][d] = dot(W_i[d,:], dWv[i,:]);  cv[i] = dot(b_i, dWv[i]) + dbv[i]
__global__ void precompute_kernel(const float* __restrict__ Wq_, const float* __restrict__ bq_,
                                  const float* __restrict__ Wk_, const float* __restrict__ bk_,
                                  const float* __restrict__ Wv_, const float* __restrict__ bv_,
                                  const float* __restrict__ Wo_, const float* __restrict__ bo_,
                                  const float* __restrict__ dWv, const float* __restrict__ dbv,
                                  float* __restrict__ wv, float* __restrict__ cv) {
  int i = blockIdx.y;
  const float* W    = (i==0)?Wq_:(i==1)?Wk_:(i==2)?Wv_:Wo_;
  const float* bvec = (i==0)?bq_:(i==1)?bk_:(i==2)?bv_:bo_;
  const float* s = dWv + i*DD;
  int t = threadIdx.x;
  __shared__ float red[256];
  float acc = 0.f;
  if (blockIdx.x < DD) {
    const float* row = W + (size_t)blockIdx.x * DD;
    for (int e = t; e < DD; e += 256) acc += row[e]*s[e];
  } else {
    for (int e = t; e < DD; e += 256) acc += bvec[e]*s[e];
  }
  red[t] = acc; __syncthreads();
  for (int off=128; off>0; off>>=1){ if(t<off) red[t]+=red[t+off]; __syncthreads(); }
  if (t==0) {
    if (blockIdx.x < DD) wv[i*DD + blockIdx.x] = red[0];
    else                 cv[i] = red[0] + dbv[i];
  }
}

// ---------------------------------------------------------------------------
// Kernel 2a: x (fp32 [M][K]) -> xb (bf16 [M][K])
__global__ void convert_x_kernel(const float* __restrict__ x, u16* __restrict__ xb) {
  size_t idx = ((size_t)blockIdx.x*256 + threadIdx.x)*8;
  float4 a = *(const float4*)(x + idx);
  float4 b = *(const float4*)(x + idx + 4);
  union { u16 u[8]; uint4 v; } pk;
  pk.u[0]=f2bf(a.x); pk.u[1]=f2bf(a.y); pk.u[2]=f2bf(a.z); pk.u[3]=f2bf(a.w);
  pk.u[4]=f2bf(b.x); pk.u[5]=f2bf(b.y); pk.u[6]=f2bf(b.z); pk.u[7]=f2bf(b.w);
  *(uint4*)(xb + idx) = pk.v;
}

// Kernel 2b: dWk fp32 [i][k][n] -> Bt bf16 [i][n][k]  (coalesced column reads)
__global__ void transpose_dwk_kernel(const float* __restrict__ dWk, u16* __restrict__ Bt) {
  int i  = blockIdx.z;
  int n  = blockIdx.x*256 + threadIdx.x;
  int ck = blockIdx.y;                       // 8-wide k chunk
  const float* src = dWk + (size_t)i*DD*DD + (size_t)ck*8*DD + n;
  union { u16 u[8]; uint4 v; } pk;
  #pragma unroll
  for (int e=0;e<8;e++) pk.u[e] = f2bf(src[(size_t)e*DD]);
  *(uint4*)(Bt + (size_t)i*DD*DD + (size_t)n*DD + ck*8) = pk.v;
}

// ---------------------------------------------------------------------------
// Kernel 3: kraw[i] = x @ dWk[i] via bf16 MFMA. A = xb [m][k], B = Bt [n][k].
// grid (8, 32, 4), block 256 (4 waves in 2x2, each wave 64x64 of C).
__global__ __launch_bounds__(256) void gemm_dwk_mfma(const u16* __restrict__ xb,
                          const u16* __restrict__ Bt, u16* __restrict__ kraw) {
  const int i = blockIdx.z;
  const u16* B = Bt + (size_t)i*DD*DD;
  u16* C = kraw + (size_t)i*MM*DD;
  const int n0 = blockIdx.x*128, m0 = blockIdx.y*128;
  const int t = threadIdx.x;
  const int w = t>>6, lane = t&63, q15 = lane&15, quad = lane>>4;
  const int wm = w>>1, wn = w&1;
  __shared__ u16 As[128*72];
  __shared__ u16 Bs[128*72];
  f32x4 acc[4][4];
  #pragma unroll
  for(int a=0;a<4;a++)
    #pragma unroll
    for(int b2=0;b2<4;b2++) acc[a][b2] = (f32x4){0.f,0.f,0.f,0.f};

  for (int k0=0; k0<DD; k0+=64) {
    __syncthreads();
    #pragma unroll
    for (int ii=0; ii<4; ii++) {
      int f = t + ii*256;
      int r = f>>3, c = f&7;
      uint4 av = *(const uint4*)(xb + (size_t)(m0+r)*DD + k0 + c*8);
      *(uint4*)(&As[r*72 + c*8]) = av;
      uint4 bv = *(const uint4*)(B  + (size_t)(n0+r)*DD + k0 + c*8);
      *(uint4*)(&Bs[r*72 + c*8]) = bv;
    }
    __syncthreads();
    #pragma unroll
    for (int kk=0; kk<2; kk++) {
      bf16x8 af[4], bfr[4];
      #pragma unroll
      for (int mt=0; mt<4; mt++)
        af[mt]  = *(bf16x8*)(&As[(wm*64+mt*16+q15)*72 + kk*32 + quad*8]);
      #pragma unroll
      for (int nt=0; nt<4; nt++)
        bfr[nt] = *(bf16x8*)(&Bs[(wn*64+nt*16+q15)*72 + kk*32 + quad*8]);
      #pragma unroll
      for (int mt=0; mt<4; mt++)
        #pragma unroll
        for (int nt=0; nt<4; nt++)
          acc[mt][nt] = __builtin_amdgcn_mfma_f32_16x16x32_bf16(af[mt], bfr[nt], acc[mt][nt], 0,0,0);
    }
  }
  #pragma unroll
  for (int mt=0; mt<4; mt++)
    #pragma unroll
    for (int nt=0; nt<4; nt++)
      #pragma unroll
      for (int r=0; r<4; r++) {
        int m = m0 + wm*64 + mt*16 + quad*4 + r;
        int n = n0 + wn*64 + nt*16 + q15;
        C[(size_t)m*DD + n] = f2bf(acc[mt][nt][r]);
      }
}

// ---------------------------------------------------------------------------
// Kernel 4: delta transform i=0..2 -> q/k/v bf16. grid (MM, 3), block 256.
__global__ void delta_qkv_kernel(const float* __restrict__ x, const u16* __restrict__ kraw,
                                 const float* __restrict__ dbw, const float* __restrict__ dbb,
                                 const float* __restrict__ wv, const float* __restrict__ cv,
                                 u16* __restrict__ qkv) {
  int m = blockIdx.x;
  int i = blockIdx.y;
  int t = threadIdx.x;
  const float* xr = x + (size_t)m*DD;
  const u16*   kr = kraw + (size_t)i*MM*DD + (size_t)m*DD;
  float4 xv  = *(const float4*)(xr + t*4);
  ushort4 ku = *(const ushort4*)(kr + t*4);
  float4 kv  = make_float4(bf2f(ku.x), bf2f(ku.y), bf2f(ku.z), bf2f(ku.w));
  float4 bwv = *(const float4*)(dbw + i*DD + t*4);
  float4 wvv = *(const float4*)(wv  + i*DD + t*4);
  __shared__ float4 red[256];
  red[t] = make_float4(dot4f(kv,kv), dot4f(kv,xv), dot4f(xv,bwv), dot4f(xv,wvv));
  __syncthreads();
  for (int off=128; off>0; off>>=1){
    if (t<off){ red[t].x+=red[t+off].x; red[t].y+=red[t+off].y;
                red[t].z+=red[t+off].z; red[t].w+=red[t+off].w; }
    __syncthreads();
  }
  __shared__ float coef_s;
  if (t==0) {
    float nrmE = sqrtf(red[0].x) + 1e-8f;
    float kdh  = red[0].y / nrmE;
    float beta = 2.f / (1.f + expf(-(red[0].z + dbb[i])));
    float vs   = red[0].w + cv[i];
    coef_s = beta * (vs - kdh) / nrmE;
  }
  __syncthreads();
  float c = coef_s;
  ushort4 ou;
  ou.x = f2bf(xv.x + c*kv.x); ou.y = f2bf(xv.y + c*kv.y);
  ou.z = f2bf(xv.z + c*kv.z); ou.w = f2bf(xv.w + c*kv.w);
  *(ushort4*)(qkv + (size_t)i*MM*DD + (size_t)m*DD + t*4) = ou;
}

// ---------------------------------------------------------------------------
// Kernel 5: bf16 MFMA flash attention. grid (SS/64, HH, BB), block 256.
// S^T = K.Q^T (both operands row-major in LDS); P via wave-local LDS round trip.
__global__ __launch_bounds__(256) void flash_mfma(const u16* __restrict__ qb,
     const u16* __restrict__ kb, const u16* __restrict__ vb, float* __restrict__ o) {
  const int b = blockIdx.z, h = blockIdx.y, qt = blockIdx.x;
  const int t = threadIdx.x, w = t>>6, lane = t&63, q15 = lane&15, quad = lane>>4;
  __shared__ u16 Qs[64*72];
  __shared__ u16 Ks[64*72];
  __shared__ u16 Vt[64*72];   // V transposed: [d][key]
  __shared__ u16 Ps[64*72];   // P: [q][key]
  __shared__ float abr[64], lbr[64];
  const size_t hb = (size_t)h*HD;
  #pragma unroll
  for (int ii=0; ii<2; ii++) {
    int f = t + ii*256; int r = f>>3, c = f&7;
    uint4 v4 = *(const uint4*)(qb + (size_t)(b*SS + qt*64 + r)*DD + hb + c*8);
    *(uint4*)(&Qs[r*72 + c*8]) = v4;
  }
  f32x4 Oacc[4];
  #pragma unroll
  for (int dt=0; dt<4; dt++) Oacc[dt] = (f32x4){0.f,0.f,0.f,0.f};
  float m_i = -1e30f, l_i = 0.f;

  for (int kt=0; kt<SS/64; kt++) {
    __syncthreads();
    #pragma unroll
    for (int ii=0; ii<2; ii++) {           // K rows -> Ks[key][d]
      int f = t + ii*256; int r = f>>3, c = f&7;
      uint4 v4 = *(const uint4*)(kb + (size_t)(b*SS + kt*64 + r)*DD + hb + c*8);
      *(uint4*)(&Ks[r*72 + c*8]) = v4;
    }
    #pragma unroll
    for (int ii=0; ii<2; ii++) {           // V -> Vt[d][key] (scatter transpose)
      int f = t + ii*256; int key = f&63, c = f>>6;
      union { uint4 v; u16 u[8]; } pk;
      pk.v = *(const uint4*)(vb + (size_t)(b*SS + kt*64 + key)*DD + hb + c*8);
      #pragma unroll
      for (int e=0; e<8; e++) Vt[(c*8+e)*72 + key] = pk.u[e];
    }
    __syncthreads();
    // S^T tiles: rows = keys (rt*16 + quad*4 + r), cols = q (w*16 + q15)
    f32x4 Sacc[4];
    #pragma unroll
    for (int rt=0; rt<4; rt++) Sacc[rt] = (f32x4){0.f,0.f,0.f,0.f};
    #pragma unroll
    for (int kk=0; kk<2; kk++) {
      bf16x8 qf = *(bf16x8*)(&Qs[(w*16+q15)*72 + kk*32 + quad*8]);
      #pragma unroll
      for (int rt=0; rt<4; rt++) {
        bf16x8 kf = *(bf16x8*)(&Ks[(rt*16+q15)*72 + kk*32 + quad*8]);
        Sacc[rt] = __builtin_amdgcn_mfma_f32_16x16x32_bf16(kf, qf, Sacc[rt], 0,0,0);
      }
    }
    // online softmax: each lane holds 16 keys of ONE q (= w*16+q15)
    float mx = -1e30f;
    #pragma unroll
    for (int rt=0; rt<4; rt++)
      #pragma unroll
      for (int r=0; r<4; r++) { Sacc[rt][r] *= 0.125f; mx = fmaxf(mx, Sacc[rt][r]); }
    mx = fmaxf(mx, __shfl_xor(mx, 16));
    mx = fmaxf(mx, __shfl_xor(mx, 32));
    float mn = fmaxf(m_i, mx);
    float alpha = __expf(m_i - mn);
    m_i = mn;
    float p[4][4], sm = 0.f;
    #pragma unroll
    for (int rt=0; rt<4; rt++)
      #pragma unroll
      for (int r=0; r<4; r++) { p[rt][r] = __expf(Sacc[rt][r] - mn); sm += p[rt][r]; }
    sm += __shfl_xor(sm, 16);
    sm += __shfl_xor(sm, 32);
    l_i = l_i*alpha + sm;
    if (quad==0) abr[w*16 + q15] = alpha;   // broadcast alpha to C-layout lanes
    // write P -> Ps[q][key], 4 packed bf16 per rt (keys rt*16+quad*4..+3)
    #pragma unroll
    for (int rt=0; rt<4; rt++) {
      union { u16 u[4]; uint2 v; } pp;
      #pragma unroll
      for (int r=0; r<4; r++) pp.u[r] = f2bf(p[rt][r]);
      *(uint2*)(&Ps[(w*16+q15)*72 + rt*16 + quad*4]) = pp.v;
    }
    float ab[4];
    #pragma unroll
    for (int r=0; r<4; r++) ab[r] = abr[w*16 + quad*4 + r];
    #pragma unroll
    for (int dt=0; dt<4; dt++)
      #pragma unroll
      for (int r=0; r<4; r++) Oacc[dt][r] *= ab[r];
    // PV: O[q][d] += P[q][key] * V[key][d]
    #pragma unroll
    for (int kh=0; kh<2; kh++) {
      bf16x8 pf = *(bf16x8*)(&Ps[(w*16+q15)*72 + kh*32 + quad*8]);
      #pragma unroll
      for (int dt=0; dt<4; dt++) {
        bf16x8 vf = *(bf16x8*)(&Vt[(dt*16+q15)*72 + kh*32 + quad*8]);
        Oacc[dt] = __builtin_amdgcn_mfma_f32_16x16x32_bf16(pf, vf, Oacc[dt], 0,0,0);
      }
    }
  }
  if (quad==0) lbr[w*16 + q15] = 1.f/l_i;
  float li[4];
  #pragma unroll
  for (int r=0; r<4; r++) li[r] = lbr[w*16 + quad*4 + r];
  #pragma unroll
  for (int dt=0; dt<4; dt++)
    #pragma unroll
    for (int r=0; r<4; r++) {
      int s = qt*64 + w*16 + quad*4 + r;
      o[(size_t)(b*SS + s)*DD + hb + dt*16 + q15] = Oacc[dt][r]*li[r];
    }
}

// ---------------------------------------------------------------------------
// Kernel 6: delta #3 (v3 from attn.wv3) + LayerNorm. grid MM, block 256.
__global__ void final_kernel(const float* __restrict__ x, const u16* __restrict__ kraw3,
                             const float* __restrict__ attn,
                             const float* __restrict__ dbw, const float* __restrict__ dbb,
                             const float* __restrict__ wv, const float* __restrict__ cv,
                             const float* __restrict__ ln_g, const float* __restrict__ ln_b,
                             float* __restrict__ out) {
  int m = blockIdx.x; int t = threadIdx.x;
  const float* xr = x    + (size_t)m*DD;
  const u16*   kr = kraw3 + (size_t)m*DD;
  const float* ar = attn + (size_t)m*DD;
  float4 xv  = *(const float4*)(xr + t*4);
  ushort4 ku = *(const ushort4*)(kr + t*4);
  float4 kv  = make_float4(bf2f(ku.x), bf2f(ku.y), bf2f(ku.z), bf2f(ku.w));
  float4 av  = *(const float4*)(ar + t*4);
  float4 bwv = *(const float4*)(dbw + 3*DD + t*4);
  float4 wvv = *(const float4*)(wv  + 3*DD + t*4);
  __shared__ float4 red[256];
  red[t] = make_float4(dot4f(kv,kv), dot4f(kv,xv), dot4f(xv,bwv), dot4f(av,wvv));
  __syncthreads();
  for (int off=128; off>0; off>>=1){
    if (t<off){ red[t].x+=red[t+off].x; red[t].y+=red[t+off].y;
                red[t].z+=red[t+off].z; red[t].w+=red[t+off].w; }
    __syncthreads();
  }
  __shared__ float coef_s;
  if (t==0) {
    float nrmE = sqrtf(red[0].x) + 1e-8f;
    float kdh  = red[0].y / nrmE;
    float beta = 2.f / (1.f + expf(-(red[0].z + dbb[3])));
    float v3   = red[0].w + cv[3];
    coef_s = beta * (v3 - kdh) / nrmE;
  }
  __syncthreads();
  float c = coef_s;
  float y0 = xv.x + c*kv.x, y1 = xv.y + c*kv.y, y2 = xv.z + c*kv.z, y3 = xv.w + c*kv.w;
  red[t] = make_float4(y0+y1+y2+y3, y0*y0+y1*y1+y2*y2+y3*y3, 0.f, 0.f);
  __syncthreads();
  for (int off=128; off>0; off>>=1){
    if (t<off){ red[t].x+=red[t+off].x; red[t].y+=red[t+off].y; }
    __syncthreads();
  }
  __shared__ float2 stats_s;
  if (t==0) {
    float mu  = red[0].x * (1.f/DD);
    float var = red[0].y * (1.f/DD) - mu*mu;
    stats_s = make_float2(mu, rsqrtf(var + 1e-5f));
  }
  __syncthreads();
  float mu = stats_s.x, rstd = stats_s.y;
  float4 g  = *(const float4*)(ln_g + t*4);
  float4 bb = *(const float4*)(ln_b + t*4);
  float4 ov;
  ov.x = (y0-mu)*rstd*g.x + bb.x;
  ov.y = (y1-mu)*rstd*g.y + bb.y;
  ov.z = (y2-mu)*rstd*g.z + bb.z;
  ov.w = (y3-mu)*rstd*g.w + bb.w;
  *(float4*)(out + (size_t)m*DD + t*4) = ov;
}

// ---------------------------------------------------------------------------
extern "C" void kernel_launch(void* const* d_in, const int* in_sizes, int n_in,
                              void* d_out, int out_size, void* d_ws, size_t ws_size,
                              hipStream_t stream) {
  const float* x    = (const float*)d_in[0];
  const float* Wq_  = (const float*)d_in[1];
  const float* bq_  = (const float*)d_in[2];
  const float* Wk_  = (const float*)d_in[3];
  const float* bk_  = (const float*)d_in[4];
  const float* Wv_  = (const float*)d_in[5];
  const float* bv_  = (const float*)d_in[6];
  const float* Wo_  = (const float*)d_in[7];
  const float* bo_  = (const float*)d_in[8];
  const float* dWk  = (const float*)d_in[9];
  const float* dbw  = (const float*)d_in[10];
  const float* dbb  = (const float*)d_in[11];
  const float* dWv  = (const float*)d_in[12];
  const float* dbv  = (const float*)d_in[13];
  const float* ln_g = (const float*)d_in[14];
  const float* ln_b = (const float*)d_in[15];
  float* out = (float*)d_out;
  char* WS = (char*)d_ws;

  // workspace layout (bytes, 16B-aligned)
  float* wv    = (float*)WS;                               // 4096 f32
  float* cv    = (float*)(WS + 4096*4);                    // 4 f32 (pad to 64 f32)
  u16*   kraw  = (u16*)  (WS + 16640);                     // 4*MM*DD bf16 = 33.5 MB
  u16*   qkvb  = (u16*)  (WS + 16640 + (size_t)4*MM*DD*2); // 3*MM*DD bf16 = 25.2 MB
  u16*   dWkT  = (u16*)  (WS + 16640 + (size_t)7*MM*DD*2); // 4*DD*DD bf16 = 8.4 MB
  u16*   xb    = (u16*)  (WS + 16640 + (size_t)7*MM*DD*2 + (size_t)4*DD*DD*2); // MM*DD bf16
  float* attn  = (float*)kraw;   // aliases kraw[0..1] (dead after delta_qkv)

  precompute_kernel<<<dim3(DD+1, 4), 256, 0, stream>>>(Wq_,bq_,Wk_,bk_,Wv_,bv_,Wo_,bo_,dWv,dbv,wv,cv);
  convert_x_kernel<<<(MM*DD)/(256*8), 256, 0, stream>>>(x, xb);
  transpose_dwk_kernel<<<dim3(4, 128, 4), 256, 0, stream>>>(dWk, dWkT);
  gemm_dwk_mfma<<<dim3(8, 32, 4), 256, 0, stream>>>(xb, dWkT, kraw);
  delta_qkv_kernel<<<dim3(MM, 3), 256, 0, stream>>>(x, kraw, dbw, dbb, wv, cv, qkvb);
  flash_mfma<<<dim3(SS/64, HH, BB), 256, 0, stream>>>(
      qkvb, qkvb + (size_t)MM*DD, qkvb + 2*(size_t)MM*DD, attn);
  final_kernel<<<MM, 256, 0, stream>>>(x, kraw + 3*(size_t)MM*DD, attn,
                                       dbw, dbb, wv, cv, ln_g, ln_b, out);
}

// Round 3
// 286.662 us; speedup vs baseline: 4.1848x; 1.0117x over previous
//
#include <hip/hip_runtime.h>

#define BB 2
#define SS 2048
#define DD 1024
#define HH 16
#define HD 64
#define MM (BB*SS)   // 4096

typedef unsigned short u16;
typedef __attribute__((ext_vector_type(8))) short bf16x8;
typedef __attribute__((ext_vector_type(4))) float f32x4;

typedef __attribute__((address_space(1))) const unsigned int* gas_t;
typedef __attribute__((address_space(3))) unsigned int* las_t;

__device__ __forceinline__ void gl_lds16(const u16* g, u16* l){
  // 16B per lane; LDS dest = wave-uniform base + lane*16 (m97 pattern)
  __builtin_amdgcn_global_load_lds((gas_t)g, (las_t)l, 16, 0, 0);
}

__device__ __forceinline__ u16 f2bf(float f){
  unsigned u = __float_as_uint(f);
  u += 0x7FFF + ((u >> 16) & 1);      // round-to-nearest-even
  return (u16)(u >> 16);
}
__device__ __forceinline__ float bf2f(u16 h){
  return __uint_as_float(((unsigned)h) << 16);
}
__device__ __forceinline__ float dot4f(float4 a, float4 b){
  return a.x*b.x + a.y*b.y + a.z*b.z + a.w*b.w;
}

// ---------------------------------------------------------------------------
// Kernel 1: wv[i][d] = dot(W_i[d,:], dWv[i,:]);  cv[i] = dot(b_i, dWv[i]) + dbv[i]
__global__ void precompute_kernel(const float* __restrict__ Wq_, const float* __restrict__ bq_,
                                  const float* __restrict__ Wk_, const float* __restrict__ bk_,
                                  const float* __restrict__ Wv_, const float* __restrict__ bv_,
                                  const float* __restrict__ Wo_, const float* __restrict__ bo_,
                                  const float* __restrict__ dWv, const float* __restrict__ dbv,
                                  float* __restrict__ wv, float* __restrict__ cv) {
  int i = blockIdx.y;
  const float* W    = (i==0)?Wq_:(i==1)?Wk_:(i==2)?Wv_:Wo_;
  const float* bvec = (i==0)?bq_:(i==1)?bk_:(i==2)?bv_:bo_;
  const float* s = dWv + i*DD;
  int t = threadIdx.x;
  __shared__ float red[256];
  float acc = 0.f;
  if (blockIdx.x < DD) {
    const float* row = W + (size_t)blockIdx.x * DD;
    for (int e = t; e < DD; e += 256) acc += row[e]*s[e];
  } else {
    for (int e = t; e < DD; e += 256) acc += bvec[e]*s[e];
  }
  red[t] = acc; __syncthreads();
  for (int off=128; off>0; off>>=1){ if(t<off) red[t]+=red[t+off]; __syncthreads(); }
  if (t==0) {
    if (blockIdx.x < DD) wv[i*DD + blockIdx.x] = red[0];
    else                 cv[i] = red[0] + dbv[i];
  }
}

// ---------------------------------------------------------------------------
// Kernel 2a: x (fp32 [M][K]) -> xb (bf16 [M][K])
__global__ void convert_x_kernel(const float* __restrict__ x, u16* __restrict__ xb) {
  size_t idx = ((size_t)blockIdx.x*256 + threadIdx.x)*8;
  float4 a = *(const float4*)(x + idx);
  float4 b = *(const float4*)(x + idx + 4);
  union { u16 u[8]; uint4 v; } pk;
  pk.u[0]=f2bf(a.x); pk.u[1]=f2bf(a.y); pk.u[2]=f2bf(a.z); pk.u[3]=f2bf(a.w);
  pk.u[4]=f2bf(b.x); pk.u[5]=f2bf(b.y); pk.u[6]=f2bf(b.z); pk.u[7]=f2bf(b.w);
  *(uint4*)(xb + idx) = pk.v;
}

// Kernel 2b: dWk fp32 [i][k][n] -> Bt bf16 [i][n][k]  (coalesced column reads)
__global__ void transpose_dwk_kernel(const float* __restrict__ dWk, u16* __restrict__ Bt) {
  int i  = blockIdx.z;
  int n  = blockIdx.x*256 + threadIdx.x;
  int ck = blockIdx.y;                       // 8-wide k chunk
  const float* src = dWk + (size_t)i*DD*DD + (size_t)ck*8*DD + n;
  union { u16 u[8]; uint4 v; } pk;
  #pragma unroll
  for (int e=0;e<8;e++) pk.u[e] = f2bf(src[(size_t)e*DD]);
  *(uint4*)(Bt + (size_t)i*DD*DD + (size_t)n*DD + ck*8) = pk.v;
}

// ---------------------------------------------------------------------------
// Kernel 3: kraw[i] = x @ dWk[i], bf16 MFMA, m97 structure:
// global_load_lds width=16 into unpadded [128][64] tiles, XOR colgroup swizzle.
// grid (8, 32, 4), block 256 (4 waves 2x2, each wave 64x64 of C).
__global__ __launch_bounds__(256) void gemm_dwk_mfma(const u16* __restrict__ xb,
                          const u16* __restrict__ Bt, u16* __restrict__ kraw) {
  const int i = blockIdx.z;
  const u16* Bm = Bt + (size_t)i*DD*DD;
  u16* C = kraw + (size_t)i*MM*DD;
  const int n0 = blockIdx.x*128, m0 = blockIdx.y*128;
  const int t = threadIdx.x, w = t>>6, lane = t&63;
  const int q15 = lane&15, quad = lane>>4;
  const int wm = w>>1, wn = w&1;
  const int lr = lane>>3, lc = lane&7, gsw = lc ^ lr;  // staging-side swizzle
  const int sw = q15 & 7;                              // read-side swizzle
  __shared__ u16 As[128*64];
  __shared__ u16 Bs[128*64];
  f32x4 acc[4][4];
  #pragma unroll
  for(int a=0;a<4;a++)
    #pragma unroll
    for(int b2=0;b2<4;b2++) acc[a][b2] = (f32x4){0.f,0.f,0.f,0.f};

  for (int k0=0; k0<DD; k0+=64) {
    __syncthreads();
    #pragma unroll
    for (int j=0; j<4; j++) {
      int r = (w*4+j)*8 + lr;           // 0..127, r&7 == lr
      gl_lds16(xb + (size_t)(m0+r)*DD + k0 + gsw*8, &As[((w*4+j)*8)*64]);
      gl_lds16(Bm + (size_t)(n0+r)*DD + k0 + gsw*8, &Bs[((w*4+j)*8)*64]);
    }
    __syncthreads();
    #pragma unroll
    for (int kk=0; kk<2; kk++) {
      bf16x8 af[4], bfr[4];
      #pragma unroll
      for (int mt=0; mt<4; mt++)
        af[mt]  = *(bf16x8*)(&As[(wm*64+mt*16+q15)*64 + ((kk*4+quad)^sw)*8]);
      #pragma unroll
      for (int nt=0; nt<4; nt++)
        bfr[nt] = *(bf16x8*)(&Bs[(wn*64+nt*16+q15)*64 + ((kk*4+quad)^sw)*8]);
      #pragma unroll
      for (int mt=0; mt<4; mt++)
        #pragma unroll
        for (int nt=0; nt<4; nt++)
          acc[mt][nt] = __builtin_amdgcn_mfma_f32_16x16x32_bf16(af[mt], bfr[nt], acc[mt][nt], 0,0,0);
    }
  }
  #pragma unroll
  for (int mt=0; mt<4; mt++)
    #pragma unroll
    for (int nt=0; nt<4; nt++)
      #pragma unroll
      for (int r=0; r<4; r++) {
        int m = m0 + wm*64 + mt*16 + quad*4 + r;
        int n = n0 + wn*64 + nt*16 + q15;
        C[(size_t)m*DD + n] = f2bf(acc[mt][nt][r]);
      }
}

// ---------------------------------------------------------------------------
// Kernel 4: delta transform i=0..2 fused -> q/k/v bf16. grid MM, block 256.
__global__ void delta_qkv_kernel(const float* __restrict__ x, const u16* __restrict__ kraw,
                                 const float* __restrict__ dbw, const float* __restrict__ dbb,
                                 const float* __restrict__ wv, const float* __restrict__ cv,
                                 u16* __restrict__ qkv) {
  int m = blockIdx.x, t = threadIdx.x, w = t>>6, lane = t&63;
  const float* xr = x + (size_t)m*DD;
  float4 xv = *(const float4*)(xr + t*4);
  __shared__ float4 part[3][4];
  float4 kvs[3];
  #pragma unroll
  for (int i=0;i<3;i++) {
    ushort4 ku = *(const ushort4*)(kraw + (size_t)i*MM*DD + (size_t)m*DD + t*4);
    float4 kv = make_float4(bf2f(ku.x), bf2f(ku.y), bf2f(ku.z), bf2f(ku.w));
    kvs[i] = kv;
    float4 bwv = *(const float4*)(dbw + i*DD + t*4);
    float4 wvv = *(const float4*)(wv  + i*DD + t*4);
    float4 red = make_float4(dot4f(kv,kv), dot4f(kv,xv), dot4f(xv,bwv), dot4f(xv,wvv));
    #pragma unroll
    for (int off=32; off>0; off>>=1) {
      red.x += __shfl_xor(red.x, off);
      red.y += __shfl_xor(red.y, off);
      red.z += __shfl_xor(red.z, off);
      red.w += __shfl_xor(red.w, off);
    }
    if (lane==0) part[i][w] = red;
  }
  __syncthreads();
  #pragma unroll
  for (int i=0;i<3;i++) {
    float4 r0=part[i][0], r1=part[i][1], r2=part[i][2], r3=part[i][3];
    float s0=r0.x+r1.x+r2.x+r3.x, s1=r0.y+r1.y+r2.y+r3.y;
    float s2=r0.z+r1.z+r2.z+r3.z, s3=r0.w+r1.w+r2.w+r3.w;
    float nrmE = sqrtf(s0) + 1e-8f;
    float kdh  = s1 / nrmE;
    float beta = 2.f / (1.f + __expf(-(s2 + dbb[i])));
    float vs   = s3 + cv[i];
    float c = beta * (vs - kdh) / nrmE;
    float4 kv = kvs[i];
    ushort4 ou;
    ou.x = f2bf(xv.x + c*kv.x); ou.y = f2bf(xv.y + c*kv.y);
    ou.z = f2bf(xv.z + c*kv.z); ou.w = f2bf(xv.w + c*kv.w);
    *(ushort4*)(qkv + (size_t)i*MM*DD + (size_t)m*DD + t*4) = ou;
  }
}

// ---------------------------------------------------------------------------
// Kernel 5: v (bf16 [b*S][D]) -> vT (bf16 [b][h][d][s]). grid (32,16,2), block 256.
__global__ void transpose_v_kernel(const u16* __restrict__ v, u16* __restrict__ vT) {
  int b = blockIdx.z, h = blockIdx.y, s0 = blockIdx.x*64;
  int t = threadIdx.x;
  __shared__ u16 Ls[64*72];
  #pragma unroll
  for (int ii=0; ii<2; ii++) {
    int f = t + ii*256, r = f>>3, c = f&7;
    *(uint4*)(&Ls[r*72 + c*8]) = *(const uint4*)(v + (size_t)(b*SS+s0+r)*DD + h*64 + c*8);
  }
  __syncthreads();
  #pragma unroll
  for (int ii=0; ii<2; ii++) {
    int f = t + ii*256, d = f>>3, c = f&7;
    union { u16 u[8]; uint4 q; } o;
    #pragma unroll
    for (int e=0; e<8; e++) o.u[e] = Ls[(c*8+e)*72 + d];
    *(uint4*)(vT + ((size_t)((b*HH+h)*HD) + d)*SS + s0 + c*8) = o.q;
  }
}

// ---------------------------------------------------------------------------
// Kernel 6: bf16 MFMA flash attention, DMA-staged. grid (SS/64, HH, BB), block 256.
// S^T = K.Q^T; all three tiles staged via global_load_lds with XOR swizzle;
// P round-trips through padded LDS (wave-local).
__global__ __launch_bounds__(256) void flash_mfma(const u16* __restrict__ qb,
     const u16* __restrict__ kb, const u16* __restrict__ vT, float* __restrict__ o) {
  const int b = blockIdx.z, h = blockIdx.y, qt = blockIdx.x;
  const int t = threadIdx.x, w = t>>6, lane = t&63, q15 = lane&15, quad = lane>>4;
  const int lr = lane>>3, lc = lane&7, gsw = lc ^ lr;
  const int sw = q15 & 7;
  __shared__ u16 Qs[64*64];
  __shared__ u16 Ks[64*64];
  __shared__ u16 Vs[64*64];    // vT tile: [d][key], swizzled
  __shared__ u16 Ps[64*72];    // P: [q][key], padded (VALU-written)
  __shared__ float abr[64], lbr[64];
  const size_t hb = (size_t)h*HD;
  const size_t vbase = (size_t)((b*HH+h)*HD) * SS;
  #pragma unroll
  for (int j=0; j<2; j++) {    // stage Q once
    int r = (w*2+j)*8 + lr;
    gl_lds16(qb + (size_t)(b*SS + qt*64 + r)*DD + hb + gsw*8, &Qs[((w*2+j)*8)*64]);
  }
  f32x4 Oacc[4];
  #pragma unroll
  for (int dt=0; dt<4; dt++) Oacc[dt] = (f32x4){0.f,0.f,0.f,0.f};
  float m_i = -1e30f, l_i = 0.f;

  for (int kt=0; kt<SS/64; kt++) {
    __syncthreads();
    #pragma unroll
    for (int j=0; j<2; j++) {
      int r = (w*2+j)*8 + lr;
      gl_lds16(kb + (size_t)(b*SS + kt*64 + r)*DD + hb + gsw*8, &Ks[((w*2+j)*8)*64]);
      gl_lds16(vT + vbase + (size_t)r*SS + kt*64 + gsw*8,       &Vs[((w*2+j)*8)*64]);
    }
    __syncthreads();
    // S^T tiles: rows = keys (rt*16 + quad*4 + r), cols = q (w*16 + q15)
    f32x4 Sacc[4];
    #pragma unroll
    for (int rt=0; rt<4; rt++) Sacc[rt] = (f32x4){0.f,0.f,0.f,0.f};
    #pragma unroll
    for (int kk=0; kk<2; kk++) {
      bf16x8 qf = *(bf16x8*)(&Qs[(w*16+q15)*64 + ((kk*4+quad)^sw)*8]);
      #pragma unroll
      for (int rt=0; rt<4; rt++) {
        bf16x8 kf = *(bf16x8*)(&Ks[(rt*16+q15)*64 + ((kk*4+quad)^sw)*8]);
        Sacc[rt] = __builtin_amdgcn_mfma_f32_16x16x32_bf16(kf, qf, Sacc[rt], 0,0,0);
      }
    }
    // online softmax: each lane holds 16 keys of ONE q (= w*16+q15)
    float mx = -1e30f;
    #pragma unroll
    for (int rt=0; rt<4; rt++)
      #pragma unroll
      for (int r=0; r<4; r++) { Sacc[rt][r] *= 0.125f; mx = fmaxf(mx, Sacc[rt][r]); }
    mx = fmaxf(mx, __shfl_xor(mx, 16));
    mx = fmaxf(mx, __shfl_xor(mx, 32));
    float mn = fmaxf(m_i, mx);
    float alpha = __expf(m_i - mn);
    m_i = mn;
    float p[4][4], sm = 0.f;
    #pragma unroll
    for (int rt=0; rt<4; rt++)
      #pragma unroll
      for (int r=0; r<4; r++) { p[rt][r] = __expf(Sacc[rt][r] - mn); sm += p[rt][r]; }
    sm += __shfl_xor(sm, 16);
    sm += __shfl_xor(sm, 32);
    l_i = l_i*alpha + sm;
    if (quad==0) abr[w*16 + q15] = alpha;
    // P -> Ps[q][key], truncating pack (P in [0,1]; l_i keeps fp32 sum)
    #pragma unroll
    for (int rt=0; rt<4; rt++) {
      union { u16 u[4]; uint2 v; } pp;
      #pragma unroll
      for (int r=0; r<4; r++) pp.u[r] = (u16)(__float_as_uint(p[rt][r]) >> 16);
      *(uint2*)(&Ps[(w*16+q15)*72 + rt*16 + quad*4]) = pp.v;
    }
    float ab[4];
    #pragma unroll
    for (int r=0; r<4; r++) ab[r] = abr[w*16 + quad*4 + r];
    #pragma unroll
    for (int dt=0; dt<4; dt++)
      #pragma unroll
      for (int r=0; r<4; r++) Oacc[dt][r] *= ab[r];
    // PV: O[q][d] += P[q][key] * V[key][d]
    #pragma unroll
    for (int kh=0; kh<2; kh++) {
      bf16x8 pf = *(bf16x8*)(&Ps[(w*16+q15)*72 + kh*32 + quad*8]);
      #pragma unroll
      for (int dt=0; dt<4; dt++) {
        bf16x8 vf = *(bf16x8*)(&Vs[(dt*16+q15)*64 + ((kh*4+quad)^sw)*8]);
        Oacc[dt] = __builtin_amdgcn_mfma_f32_16x16x32_bf16(pf, vf, Oacc[dt], 0,0,0);
      }
    }
  }
  if (quad==0) lbr[w*16 + q15] = 1.f/l_i;
  float li[4];
  #pragma unroll
  for (int r=0; r<4; r++) li[r] = lbr[w*16 + quad*4 + r];
  #pragma unroll
  for (int dt=0; dt<4; dt++)
    #pragma unroll
    for (int r=0; r<4; r++) {
      int s = qt*64 + w*16 + quad*4 + r;
      o[(size_t)(b*SS + s)*DD + hb + dt*16 + q15] = Oacc[dt][r]*li[r];
    }
}

// ---------------------------------------------------------------------------
// Kernel 7: delta #3 (v3 from attn.wv3) + LayerNorm. grid MM, block 256.
__global__ void final_kernel(const float* __restrict__ x, const u16* __restrict__ kraw3,
                             const float* __restrict__ attn,
                             const float* __restrict__ dbw, const float* __restrict__ dbb,
                             const float* __restrict__ wv, const float* __restrict__ cv,
                             const float* __restrict__ ln_g, const float* __restrict__ ln_b,
                             float* __restrict__ out) {
  int m = blockIdx.x, t = threadIdx.x, w = t>>6, lane = t&63;
  const float* xr = x    + (size_t)m*DD;
  const u16*   kr = kraw3 + (size_t)m*DD;
  const float* ar = attn + (size_t)m*DD;
  float4 xv  = *(const float4*)(xr + t*4);
  ushort4 ku = *(const ushort4*)(kr + t*4);
  float4 kv  = make_float4(bf2f(ku.x), bf2f(ku.y), bf2f(ku.z), bf2f(ku.w));
  float4 av  = *(const float4*)(ar + t*4);
  float4 bwv = *(const float4*)(dbw + 3*DD + t*4);
  float4 wvv = *(const float4*)(wv  + 3*DD + t*4);
  __shared__ float4 part[4];
  __shared__ float2 part2[4];
  float4 red = make_float4(dot4f(kv,kv), dot4f(kv,xv), dot4f(xv,bwv), dot4f(av,wvv));
  #pragma unroll
  for (int off=32; off>0; off>>=1) {
    red.x += __shfl_xor(red.x, off);
    red.y += __shfl_xor(red.y, off);
    red.z += __shfl_xor(red.z, off);
    red.w += __shfl_xor(red.w, off);
  }
  if (lane==0) part[w] = red;
  __syncthreads();
  float4 r0=part[0], r1=part[1], r2=part[2], r3=part[3];
  float s0=r0.x+r1.x+r2.x+r3.x, s1=r0.y+r1.y+r2.y+r3.y;
  float s2=r0.z+r1.z+r2.z+r3.z, s3=r0.w+r1.w+r2.w+r3.w;
  float nrmE = sqrtf(s0) + 1e-8f;
  float kdh  = s1 / nrmE;
  float beta = 2.f / (1.f + __expf(-(s2 + dbb[3])));
  float v3   = s3 + cv[3];
  float c = beta * (v3 - kdh) / nrmE;
  float y0 = xv.x + c*kv.x, y1 = xv.y + c*kv.y, y2 = xv.z + c*kv.z, y3 = xv.w + c*kv.w;
  float2 rr = make_float2(y0+y1+y2+y3, y0*y0+y1*y1+y2*y2+y3*y3);
  #pragma unroll
  for (int off=32; off>0; off>>=1) {
    rr.x += __shfl_xor(rr.x, off);
    rr.y += __shfl_xor(rr.y, off);
  }
  if (lane==0) part2[w] = rr;
  __syncthreads();
  float ssum = part2[0].x+part2[1].x+part2[2].x+part2[3].x;
  float ssq  = part2[0].y+part2[1].y+part2[2].y+part2[3].y;
  float mu   = ssum * (1.f/DD);
  float var  = ssq * (1.f/DD) - mu*mu;
  float rstd = rsqrtf(var + 1e-5f);
  float4 g  = *(const float4*)(ln_g + t*4);
  float4 bb = *(const float4*)(ln_b + t*4);
  float4 ov;
  ov.x = (y0-mu)*rstd*g.x + bb.x;
  ov.y = (y1-mu)*rstd*g.y + bb.y;
  ov.z = (y2-mu)*rstd*g.z + bb.z;
  ov.w = (y3-mu)*rstd*g.w + bb.w;
  *(float4*)(out + (size_t)m*DD + t*4) = ov;
}

// ---------------------------------------------------------------------------
extern "C" void kernel_launch(void* const* d_in, const int* in_sizes, int n_in,
                              void* d_out, int out_size, void* d_ws, size_t ws_size,
                              hipStream_t stream) {
  const float* x    = (const float*)d_in[0];
  const float* Wq_  = (const float*)d_in[1];
  const float* bq_  = (const float*)d_in[2];
  const float* Wk_  = (const float*)d_in[3];
  const float* bk_  = (const float*)d_in[4];
  const float* Wv_  = (const float*)d_in[5];
  const float* bv_  = (const float*)d_in[6];
  const float* Wo_  = (const float*)d_in[7];
  const float* bo_  = (const float*)d_in[8];
  const float* dWk  = (const float*)d_in[9];
  const float* dbw  = (const float*)d_in[10];
  const float* dbb  = (const float*)d_in[11];
  const float* dWv  = (const float*)d_in[12];
  const float* dbv  = (const float*)d_in[13];
  const float* ln_g = (const float*)d_in[14];
  const float* ln_b = (const float*)d_in[15];
  float* out = (float*)d_out;
  char* WS = (char*)d_ws;

  // workspace layout (bytes):
  //  [0,16384)                      wv (4x1024 f32)
  //  [16384,16640)                  cv
  //  [16640, +33554432)             kraw  (4 x MM x DD bf16); vT aliases kraw[0] later
  //  [.., +25165824)                qkvb  (3 x MM x DD bf16)
  //  [.., +16777216)                scratch: dWkT (8.39MB) + xb (8.39MB); attn f32 aliases whole
  float* wv    = (float*)WS;
  float* cv    = (float*)(WS + 16384);
  u16*   kraw  = (u16*)  (WS + 16640);
  u16*   qkvb  = (u16*)  (WS + 16640 + (size_t)4*MM*DD*2);
  u16*   dWkT  = (u16*)  (WS + 16640 + (size_t)7*MM*DD*2);
  u16*   xb    = (u16*)  (WS + 16640 + (size_t)7*MM*DD*2 + (size_t)4*DD*DD*2);
  float* attn  = (float*)dWkT;   // alias: dWkT+xb dead after gemm
  u16*   vT    = kraw;           // alias: kraw[0..2] dead after delta_qkv (final uses kraw[3])

  precompute_kernel<<<dim3(DD+1, 4), 256, 0, stream>>>(Wq_,bq_,Wk_,bk_,Wv_,bv_,Wo_,bo_,dWv,dbv,wv,cv);
  convert_x_kernel<<<(MM*DD)/(256*8), 256, 0, stream>>>(x, xb);
  transpose_dwk_kernel<<<dim3(4, 128, 4), 256, 0, stream>>>(dWk, dWkT);
  gemm_dwk_mfma<<<dim3(8, 32, 4), 256, 0, stream>>>(xb, dWkT, kraw);
  delta_qkv_kernel<<<MM, 256, 0, stream>>>(x, kraw, dbw, dbb, wv, cv, qkvb);
  transpose_v_kernel<<<dim3(SS/64, HH, BB), 256, 0, stream>>>(qkvb + 2*(size_t)MM*DD, vT);
  flash_mfma<<<dim3(SS/64, HH, BB), 256, 0, stream>>>(
      qkvb, qkvb + (size_t)MM*DD, vT, attn);
  final_kernel<<<MM, 256, 0, stream>>>(x, kraw + 3*(size_t)MM*DD, attn,
                                       dbw, dbb, wv, cv, ln_g, ln_b, out);
}

// Round 4
// 281.325 us; speedup vs baseline: 4.2642x; 1.0190x over previous
//
#include <hip/hip_runtime.h>

#define BB 2
#define SS 2048
#define DD 1024
#define HH 16
#define HD 64
#define MM (BB*SS)   // 4096

typedef unsigned short u16;
typedef __attribute__((ext_vector_type(8))) short bf16x8;
typedef __attribute__((ext_vector_type(4))) float f32x4;

typedef __attribute__((address_space(1))) const unsigned int* gas_t;
typedef __attribute__((address_space(3))) unsigned int* las_t;

#ifndef __has_builtin
#define __has_builtin(x) 0
#endif
#if __has_builtin(__builtin_amdgcn_exp2f)
#define EXP2F(x) __builtin_amdgcn_exp2f(x)
#else
#define EXP2F(x) __expf((x)*0.6931471805599453f)
#endif
// q pre-scale: 0.125 (HD^-0.5) * log2(e), so scores come out ready for exp2
#define QSCALE 0.18033688011112042f

__device__ __forceinline__ void gl_lds16(const u16* g, u16* l){
  __builtin_amdgcn_global_load_lds((gas_t)g, (las_t)l, 16, 0, 0);
}

__device__ __forceinline__ u16 f2bf(float f){
  unsigned u = __float_as_uint(f);
  u += 0x7FFF + ((u >> 16) & 1);      // RNE
  return (u16)(u >> 16);
}
__device__ __forceinline__ float bf2f(u16 h){
  return __uint_as_float(((unsigned)h) << 16);
}
__device__ __forceinline__ float dot4f(float4 a, float4 b){
  return a.x*b.x + a.y*b.y + a.z*b.z + a.w*b.w;
}

// ---------------------------------------------------------------------------
// Kernel 1: wv[i][d] = dot(W_i[d,:], dWv[i,:]);  cv[i] = dot(b_i, dWv[i]) + dbv[i]
__global__ void precompute_kernel(const float* __restrict__ Wq_, const float* __restrict__ bq_,
                                  const float* __restrict__ Wk_, const float* __restrict__ bk_,
                                  const float* __restrict__ Wv_, const float* __restrict__ bv_,
                                  const float* __restrict__ Wo_, const float* __restrict__ bo_,
                                  const float* __restrict__ dWv, const float* __restrict__ dbv,
                                  float* __restrict__ wv, float* __restrict__ cv) {
  int i = blockIdx.y;
  const float* W    = (i==0)?Wq_:(i==1)?Wk_:(i==2)?Wv_:Wo_;
  const float* bvec = (i==0)?bq_:(i==1)?bk_:(i==2)?bv_:bo_;
  const float* s = dWv + i*DD;
  int t = threadIdx.x;
  __shared__ float red[256];
  float acc = 0.f;
  if (blockIdx.x < DD) {
    const float* row = W + (size_t)blockIdx.x * DD;
    for (int e = t; e < DD; e += 256) acc += row[e]*s[e];
  } else {
    for (int e = t; e < DD; e += 256) acc += bvec[e]*s[e];
  }
  red[t] = acc; __syncthreads();
  for (int off=128; off>0; off>>=1){ if(t<off) red[t]+=red[t+off]; __syncthreads(); }
  if (t==0) {
    if (blockIdx.x < DD) wv[i*DD + blockIdx.x] = red[0];
    else                 cv[i] = red[0] + dbv[i];
  }
}

// ---------------------------------------------------------------------------
// Kernel 2a: x (fp32 [M][K]) -> xb (bf16 [M][K])
__global__ void convert_x_kernel(const float* __restrict__ x, u16* __restrict__ xb) {
  size_t idx = ((size_t)blockIdx.x*256 + threadIdx.x)*8;
  float4 a = *(const float4*)(x + idx);
  float4 b = *(const float4*)(x + idx + 4);
  union { u16 u[8]; uint4 v; } pk;
  pk.u[0]=f2bf(a.x); pk.u[1]=f2bf(a.y); pk.u[2]=f2bf(a.z); pk.u[3]=f2bf(a.w);
  pk.u[4]=f2bf(b.x); pk.u[5]=f2bf(b.y); pk.u[6]=f2bf(b.z); pk.u[7]=f2bf(b.w);
  *(uint4*)(xb + idx) = pk.v;
}

// Kernel 2b: dWk fp32 [i][k][n] -> Bt bf16 [i][n][k]
__global__ void transpose_dwk_kernel(const float* __restrict__ dWk, u16* __restrict__ Bt) {
  int i  = blockIdx.z;
  int n  = blockIdx.x*256 + threadIdx.x;
  int ck = blockIdx.y;
  const float* src = dWk + (size_t)i*DD*DD + (size_t)ck*8*DD + n;
  union { u16 u[8]; uint4 v; } pk;
  #pragma unroll
  for (int e=0;e<8;e++) pk.u[e] = f2bf(src[(size_t)e*DD]);
  *(uint4*)(Bt + (size_t)i*DD*DD + (size_t)n*DD + ck*8) = pk.v;
}

// ---------------------------------------------------------------------------
// Kernel 3: kraw[i] = x @ dWk[i], bf16 MFMA (m97 structure; unchanged from R3).
__global__ __launch_bounds__(256) void gemm_dwk_mfma(const u16* __restrict__ xb,
                          const u16* __restrict__ Bt, u16* __restrict__ kraw) {
  const int i = blockIdx.z;
  const u16* Bm = Bt + (size_t)i*DD*DD;
  u16* C = kraw + (size_t)i*MM*DD;
  const int n0 = blockIdx.x*128, m0 = blockIdx.y*128;
  const int t = threadIdx.x, w = t>>6, lane = t&63;
  const int q15 = lane&15, quad = lane>>4;
  const int wm = w>>1, wn = w&1;
  const int lr = lane>>3, lc = lane&7, gsw = lc ^ lr;
  const int sw = q15 & 7;
  __shared__ u16 As[128*64];
  __shared__ u16 Bs[128*64];
  f32x4 acc[4][4];
  #pragma unroll
  for(int a=0;a<4;a++)
    #pragma unroll
    for(int b2=0;b2<4;b2++) acc[a][b2] = (f32x4){0.f,0.f,0.f,0.f};

  for (int k0=0; k0<DD; k0+=64) {
    __syncthreads();
    #pragma unroll
    for (int j=0; j<4; j++) {
      int r = (w*4+j)*8 + lr;
      gl_lds16(xb + (size_t)(m0+r)*DD + k0 + gsw*8, &As[((w*4+j)*8)*64]);
      gl_lds16(Bm + (size_t)(n0+r)*DD + k0 + gsw*8, &Bs[((w*4+j)*8)*64]);
    }
    __syncthreads();
    #pragma unroll
    for (int kk=0; kk<2; kk++) {
      bf16x8 af[4], bfr[4];
      #pragma unroll
      for (int mt=0; mt<4; mt++)
        af[mt]  = *(bf16x8*)(&As[(wm*64+mt*16+q15)*64 + ((kk*4+quad)^sw)*8]);
      #pragma unroll
      for (int nt=0; nt<4; nt++)
        bfr[nt] = *(bf16x8*)(&Bs[(wn*64+nt*16+q15)*64 + ((kk*4+quad)^sw)*8]);
      #pragma unroll
      for (int mt=0; mt<4; mt++)
        #pragma unroll
        for (int nt=0; nt<4; nt++)
          acc[mt][nt] = __builtin_amdgcn_mfma_f32_16x16x32_bf16(af[mt], bfr[nt], acc[mt][nt], 0,0,0);
    }
  }
  #pragma unroll
  for (int mt=0; mt<4; mt++)
    #pragma unroll
    for (int nt=0; nt<4; nt++)
      #pragma unroll
      for (int r=0; r<4; r++) {
        int m = m0 + wm*64 + mt*16 + quad*4 + r;
        int n = n0 + wn*64 + nt*16 + q15;
        C[(size_t)m*DD + n] = f2bf(acc[mt][nt][r]);
      }
}

// ---------------------------------------------------------------------------
// Kernel 4: delta i=0..2. Writes q' (pre-scaled by QSCALE) and k planes as bf16;
// for i=2 computes v values and directly the per-head dots Vw[b][h][s]=v_row.wv3_h.
// grid MM, block 256.
__global__ void delta_qkv_kernel(const float* __restrict__ x, const u16* __restrict__ kraw,
                                 const float* __restrict__ dbw, const float* __restrict__ dbb,
                                 const float* __restrict__ wv, const float* __restrict__ cv,
                                 u16* __restrict__ qk, float* __restrict__ Vw) {
  int m = blockIdx.x, t = threadIdx.x, w = t>>6, lane = t&63;
  const float* xr = x + (size_t)m*DD;
  float4 xv = *(const float4*)(xr + t*4);
  __shared__ float4 part[3][4];
  float4 kvs[3];
  #pragma unroll
  for (int i=0;i<3;i++) {
    ushort4 ku = *(const ushort4*)(kraw + (size_t)i*MM*DD + (size_t)m*DD + t*4);
    float4 kv = make_float4(bf2f(ku.x), bf2f(ku.y), bf2f(ku.z), bf2f(ku.w));
    kvs[i] = kv;
    float4 bwv = *(const float4*)(dbw + i*DD + t*4);
    float4 wvv = *(const float4*)(wv  + i*DD + t*4);
    float4 red = make_float4(dot4f(kv,kv), dot4f(kv,xv), dot4f(xv,bwv), dot4f(xv,wvv));
    #pragma unroll
    for (int off=32; off>0; off>>=1) {
      red.x += __shfl_xor(red.x, off);
      red.y += __shfl_xor(red.y, off);
      red.z += __shfl_xor(red.z, off);
      red.w += __shfl_xor(red.w, off);
    }
    if (lane==0) part[i][w] = red;
  }
  __syncthreads();
  float cc[3];
  #pragma unroll
  for (int i=0;i<3;i++) {
    float4 r0=part[i][0], r1=part[i][1], r2=part[i][2], r3=part[i][3];
    float s0=r0.x+r1.x+r2.x+r3.x, s1=r0.y+r1.y+r2.y+r3.y;
    float s2=r0.z+r1.z+r2.z+r3.z, s3=r0.w+r1.w+r2.w+r3.w;
    float nrmE = sqrtf(s0) + 1e-8f;
    float kdh  = s1 / nrmE;
    float beta = 2.f / (1.f + __expf(-(s2 + dbb[i])));
    float vs   = s3 + cv[i];
    cc[i] = beta * (vs - kdh) / nrmE;
  }
  // q plane (pre-scaled for exp2-softmax)
  {
    float c = cc[0]; float4 kv = kvs[0];
    ushort4 ou;
    ou.x = f2bf((xv.x + c*kv.x)*QSCALE); ou.y = f2bf((xv.y + c*kv.y)*QSCALE);
    ou.z = f2bf((xv.z + c*kv.z)*QSCALE); ou.w = f2bf((xv.w + c*kv.w)*QSCALE);
    *(ushort4*)(qk + (size_t)m*DD + t*4) = ou;
  }
  // k plane
  {
    float c = cc[1]; float4 kv = kvs[1];
    ushort4 ou;
    ou.x = f2bf(xv.x + c*kv.x); ou.y = f2bf(xv.y + c*kv.y);
    ou.z = f2bf(xv.z + c*kv.z); ou.w = f2bf(xv.w + c*kv.w);
    *(ushort4*)(qk + (size_t)MM*DD + (size_t)m*DD + t*4) = ou;
  }
  // v row -> per-head dots with wv3
  {
    float c = cc[2]; float4 kv = kvs[2];
    float4 vv = make_float4(xv.x + c*kv.x, xv.y + c*kv.y, xv.z + c*kv.z, xv.w + c*kv.w);
    float4 w3 = *(const float4*)(wv + 3*DD + t*4);
    float s = dot4f(vv, w3);
    #pragma unroll
    for (int off=1; off<16; off<<=1) s += __shfl_xor(s, off);
    if ((lane & 15) == 0) {
      int head = t >> 4;                 // 0..15
      int b = m >> 11, srow = m & (SS-1);
      Vw[((size_t)(b*HH + head))*SS + srow] = s;
    }
  }
}

// ---------------------------------------------------------------------------
// Kernel 5: QK^T-only flash. Per (64q, head) block: scores -> exp2 -> running
// l and p.Vw sums; one atomicAdd per (token,head) at the end. No PV, no O.
// grid (SS/64, HH, BB), block 256.
__global__ __launch_bounds__(256) void flash_mfma(const u16* __restrict__ qb,
     const u16* __restrict__ kb, const float* __restrict__ Vw,
     float* __restrict__ v3_tok) {
  const int b = blockIdx.z, h = blockIdx.y, qt = blockIdx.x;
  const int t = threadIdx.x, w = t>>6, lane = t&63, q15 = lane&15, quad = lane>>4;
  const int lr = lane>>3, lc = lane&7, gsw = lc ^ lr;
  const int sw = q15 & 7;
  __shared__ u16 Qs[64*64];
  __shared__ u16 Ks[64*64];
  __shared__ float VwS[64];
  const size_t hb = (size_t)h*HD;
  // stage Q once via DMA
  #pragma unroll
  for (int j=0; j<2; j++) {
    int r = (w*2+j)*8 + lr;
    gl_lds16(qb + (size_t)(b*SS + qt*64 + r)*DD + hb + gsw*8, &Qs[((w*2+j)*8)*64]);
  }
  // K register prefetch (tile kt=0)
  const u16* kbase = kb + (size_t)(b*SS)*DD + hb;
  const u16* kptr[2];
  uint4 kreg[2];
  #pragma unroll
  for (int j=0; j<2; j++) {
    kptr[j] = kbase + (size_t)((w*2+j)*8 + lr)*DD + gsw*8;
    kreg[j] = *(const uint4*)kptr[j];
    kptr[j] += (size_t)64*DD;
  }
  const float* vwb = Vw + (size_t)(b*HH + h)*SS;
  float vwreg = (t < 64) ? vwb[t] : 0.f;

  float l_acc = 0.f, pv_acc = 0.f;
  __syncthreads();                 // Q staged
  bf16x8 qf[2];
  #pragma unroll
  for (int kk=0; kk<2; kk++)
    qf[kk] = *(bf16x8*)(&Qs[(w*16+q15)*64 + ((kk*4+quad)^sw)*8]);

  for (int kt=0; kt<SS/64; kt++) {
    __syncthreads();               // Ks/VwS consumers done
    #pragma unroll
    for (int j=0; j<2; j++)
      *(uint4*)(&Ks[((w*2+j)*8 + lr)*64 + gsw*8]) = kreg[j];
    if (t < 64) VwS[t] = vwreg;
    // prefetch next tile (last iteration reads stay inside workspace; unused)
    if (kt < SS/64 - 1) {
      #pragma unroll
      for (int j=0; j<2; j++) {
        kreg[j] = *(const uint4*)kptr[j];
        kptr[j] += (size_t)64*DD;
      }
      vwreg = (t < 64) ? vwb[(kt+1)*64 + t] : 0.f;
    }
    __syncthreads();
    // S^T tiles: rows = keys (rt*16 + quad*4 + r), cols = q (w*16 + q15)
    f32x4 Sacc[4];
    #pragma unroll
    for (int rt=0; rt<4; rt++) Sacc[rt] = (f32x4){0.f,0.f,0.f,0.f};
    #pragma unroll
    for (int kk=0; kk<2; kk++) {
      #pragma unroll
      for (int rt=0; rt<4; rt++) {
        bf16x8 kf = *(bf16x8*)(&Ks[(rt*16+q15)*64 + ((kk*4+quad)^sw)*8]);
        Sacc[rt] = __builtin_amdgcn_mfma_f32_16x16x32_bf16(kf, qf[kk], Sacc[rt], 0,0,0);
      }
    }
    #pragma unroll
    for (int rt=0; rt<4; rt++) {
      float4 vw4 = *(const float4*)(&VwS[rt*16 + quad*4]);   // broadcast read
      float va[4] = {vw4.x, vw4.y, vw4.z, vw4.w};
      #pragma unroll
      for (int r=0; r<4; r++) {
        float p = EXP2F(fminf(Sacc[rt][r], 30.f));
        l_acc  += p;
        pv_acc += p * va[r];
      }
    }
  }
  // reduce across quads (lanes sharing q column q15)
  l_acc  += __shfl_xor(l_acc, 16);  l_acc  += __shfl_xor(l_acc, 32);
  pv_acc += __shfl_xor(pv_acc, 16); pv_acc += __shfl_xor(pv_acc, 32);
  if (quad == 0) {
    int tok = b*SS + qt*64 + w*16 + q15;
    atomicAdd(&v3_tok[tok], pv_acc / l_acc);
  }
}

// ---------------------------------------------------------------------------
// Kernel 6: delta #3 (v3 from v3_tok scalar) + LayerNorm. grid MM, block 256.
__global__ void final_kernel(const float* __restrict__ x, const u16* __restrict__ kraw3,
                             const float* __restrict__ v3_tok,
                             const float* __restrict__ dbw, const float* __restrict__ dbb,
                             const float* __restrict__ cv,
                             const float* __restrict__ ln_g, const float* __restrict__ ln_b,
                             float* __restrict__ out) {
  int m = blockIdx.x, t = threadIdx.x, w = t>>6, lane = t&63;
  const float* xr = x     + (size_t)m*DD;
  const u16*   kr = kraw3 + (size_t)m*DD;
  float4 xv  = *(const float4*)(xr + t*4);
  ushort4 ku = *(const ushort4*)(kr + t*4);
  float4 kv  = make_float4(bf2f(ku.x), bf2f(ku.y), bf2f(ku.z), bf2f(ku.w));
  float4 bwv = *(const float4*)(dbw + 3*DD + t*4);
  __shared__ float4 part[4];
  __shared__ float2 part2[4];
  float4 red = make_float4(dot4f(kv,kv), dot4f(kv,xv), dot4f(xv,bwv), 0.f);
  #pragma unroll
  for (int off=32; off>0; off>>=1) {
    red.x += __shfl_xor(red.x, off);
    red.y += __shfl_xor(red.y, off);
    red.z += __shfl_xor(red.z, off);
  }
  if (lane==0) part[w] = red;
  __syncthreads();
  float4 r0=part[0], r1=part[1], r2=part[2], r3=part[3];
  float s0=r0.x+r1.x+r2.x+r3.x, s1=r0.y+r1.y+r2.y+r3.y, s2=r0.z+r1.z+r2.z+r3.z;
  float nrmE = sqrtf(s0) + 1e-8f;
  float kdh  = s1 / nrmE;
  float beta = 2.f / (1.f + __expf(-(s2 + dbb[3])));
  float v3   = v3_tok[m] + cv[3];
  float c = beta * (v3 - kdh) / nrmE;
  float y0 = xv.x + c*kv.x, y1 = xv.y + c*kv.y, y2 = xv.z + c*kv.z, y3 = xv.w + c*kv.w;
  float2 rr = make_float2(y0+y1+y2+y3, y0*y0+y1*y1+y2*y2+y3*y3);
  #pragma unroll
  for (int off=32; off>0; off>>=1) {
    rr.x += __shfl_xor(rr.x, off);
    rr.y += __shfl_xor(rr.y, off);
  }
  if (lane==0) part2[w] = rr;
  __syncthreads();
  float ssum = part2[0].x+part2[1].x+part2[2].x+part2[3].x;
  float ssq  = part2[0].y+part2[1].y+part2[2].y+part2[3].y;
  float mu   = ssum * (1.f/DD);
  float var  = ssq * (1.f/DD) - mu*mu;
  float rstd = rsqrtf(var + 1e-5f);
  float4 g  = *(const float4*)(ln_g + t*4);
  float4 bb = *(const float4*)(ln_b + t*4);
  float4 ov;
  ov.x = (y0-mu)*rstd*g.x + bb.x;
  ov.y = (y1-mu)*rstd*g.y + bb.y;
  ov.z = (y2-mu)*rstd*g.z + bb.z;
  ov.w = (y3-mu)*rstd*g.w + bb.w;
  *(float4*)(out + (size_t)m*DD + t*4) = ov;
}

// ---------------------------------------------------------------------------
extern "C" void kernel_launch(void* const* d_in, const int* in_sizes, int n_in,
                              void* d_out, int out_size, void* d_ws, size_t ws_size,
                              hipStream_t stream) {
  const float* x    = (const float*)d_in[0];
  const float* Wq_  = (const float*)d_in[1];
  const float* bq_  = (const float*)d_in[2];
  const float* Wk_  = (const float*)d_in[3];
  const float* bk_  = (const float*)d_in[4];
  const float* Wv_  = (const float*)d_in[5];
  const float* bv_  = (const float*)d_in[6];
  const float* Wo_  = (const float*)d_in[7];
  const float* bo_  = (const float*)d_in[8];
  const float* dWk  = (const float*)d_in[9];
  const float* dbw  = (const float*)d_in[10];
  const float* dbb  = (const float*)d_in[11];
  const float* dWv  = (const float*)d_in[12];
  const float* dbv  = (const float*)d_in[13];
  const float* ln_g = (const float*)d_in[14];
  const float* ln_b = (const float*)d_in[15];
  float* out = (float*)d_out;
  char* WS = (char*)d_ws;

  // workspace layout (bytes):
  float* wv     = (float*)WS;                                 // 16 KB
  float* cv     = (float*)(WS + 16384);                       // 256 B
  u16*   kraw   = (u16*)  (WS + 16640);                       // 4*MM*DD bf16 = 33.5 MB
  u16*   qk     = (u16*)  (WS + 16640 + (size_t)4*MM*DD*2);   // 2*MM*DD bf16 = 16.8 MB
  u16*   dWkT   = (u16*)  (WS + 16640 + (size_t)6*MM*DD*2);   // 8.4 MB
  u16*   xb     = (u16*)  (WS + 16640 + (size_t)6*MM*DD*2 + (size_t)4*DD*DD*2); // 8.4 MB
  char*  tail   = WS + 16640 + (size_t)6*MM*DD*2 + (size_t)8*DD*DD*2;
  float* Vw     = (float*)tail;                               // BB*HH*SS f32 = 256 KB
  float* v3_tok = (float*)(tail + (size_t)BB*HH*SS*4);        // MM f32 = 16 KB

  hipMemsetAsync(v3_tok, 0, MM*sizeof(float), stream);
  precompute_kernel<<<dim3(DD+1, 4), 256, 0, stream>>>(Wq_,bq_,Wk_,bk_,Wv_,bv_,Wo_,bo_,dWv,dbv,wv,cv);
  convert_x_kernel<<<(MM*DD)/(256*8), 256, 0, stream>>>(x, xb);
  transpose_dwk_kernel<<<dim3(4, 128, 4), 256, 0, stream>>>(dWk, dWkT);
  gemm_dwk_mfma<<<dim3(8, 32, 4), 256, 0, stream>>>(xb, dWkT, kraw);
  delta_qkv_kernel<<<MM, 256, 0, stream>>>(x, kraw, dbw, dbb, wv, cv, qk, Vw);
  flash_mfma<<<dim3(SS/64, HH, BB), 256, 0, stream>>>(
      qk, qk + (size_t)MM*DD, Vw, v3_tok);
  final_kernel<<<MM, 256, 0, stream>>>(x, kraw + 3*(size_t)MM*DD, v3_tok,
                                       dbw, dbb, cv, ln_g, ln_b, out);
}

// Round 5
// 238.842 us; speedup vs baseline: 5.0227x; 1.1779x over previous
//
#include <hip/hip_runtime.h>

#define BB 2
#define SS 2048
#define DD 1024
#define HH 16
#define HD 64
#define MM (BB*SS)   // 4096
#define KC 4                 // flash split-K chunks
#define KT_PER (SS/64/KC)    // 8 tiles per chunk

typedef unsigned short u16;
typedef __attribute__((ext_vector_type(8))) short bf16x8;
typedef __attribute__((ext_vector_type(4))) float f32x4;

typedef __attribute__((address_space(1))) const unsigned int* gas_t;
typedef __attribute__((address_space(3))) unsigned int* las_t;

#ifndef __has_builtin
#define __has_builtin(x) 0
#endif
#if __has_builtin(__builtin_amdgcn_exp2f)
#define EXP2F(x) __builtin_amdgcn_exp2f(x)
#else
#define EXP2F(x) __expf((x)*0.6931471805599453f)
#endif
// q pre-scale: HD^-0.5 * log2(e): scores come out of MFMA ready for exp2
#define QSCALE 0.18033688011112042f

__device__ __forceinline__ void gl_lds16(const u16* g, u16* l){
  __builtin_amdgcn_global_load_lds((gas_t)g, (las_t)l, 16, 0, 0);
}

__device__ __forceinline__ u16 f2bf(float f){
  unsigned u = __float_as_uint(f);
  u += 0x7FFF + ((u >> 16) & 1);      // RNE
  return (u16)(u >> 16);
}
__device__ __forceinline__ float bf2f(u16 h){
  return __uint_as_float(((unsigned)h) << 16);
}
__device__ __forceinline__ float dot4f(float4 a, float4 b){
  return a.x*b.x + a.y*b.y + a.z*b.z + a.w*b.w;
}

// ---------------------------------------------------------------------------
// Kernel 1 (fused prologue), 1-D grid of 8260 blocks:
//  [0,2048)      convert x -> xb (bf16)
//  [2048,4096)   transpose dWk -> dWkT (bf16 [i][n][k])
//  [4096,8196)   precompute wv[i][:], cv[i]
//  [8196,8260)   zero l_arr/pv_arr (131072 floats)
#define NB_CONV 2048
#define NB_TRAN 2048
#define NB_PREC 4100
#define NB_ZERO 64
__global__ void prep_kernel(const float* __restrict__ x, u16* __restrict__ xb,
                            const float* __restrict__ dWk, u16* __restrict__ dWkT,
                            const float* __restrict__ Wq_, const float* __restrict__ bq_,
                            const float* __restrict__ Wk_, const float* __restrict__ bk_,
                            const float* __restrict__ Wv_, const float* __restrict__ bv_,
                            const float* __restrict__ Wo_, const float* __restrict__ bo_,
                            const float* __restrict__ dWv, const float* __restrict__ dbv,
                            float* __restrict__ wv, float* __restrict__ cv,
                            float* __restrict__ lpv_zero) {
  int blk = blockIdx.x, t = threadIdx.x;
  if (blk < NB_CONV) {
    size_t idx = ((size_t)blk*256 + t)*8;
    float4 a = *(const float4*)(x + idx);
    float4 b = *(const float4*)(x + idx + 4);
    union { u16 u[8]; uint4 v; } pk;
    pk.u[0]=f2bf(a.x); pk.u[1]=f2bf(a.y); pk.u[2]=f2bf(a.z); pk.u[3]=f2bf(a.w);
    pk.u[4]=f2bf(b.x); pk.u[5]=f2bf(b.y); pk.u[6]=f2bf(b.z); pk.u[7]=f2bf(b.w);
    *(uint4*)(xb + idx) = pk.v;
    return;
  }
  blk -= NB_CONV;
  if (blk < NB_TRAN) {
    int xi = blk & 3, rest = blk >> 2;       // xi: n-block, rest: ck + 128*i
    int ck = rest & 127, i = rest >> 7;
    int n  = xi*256 + t;
    const float* src = dWk + (size_t)i*DD*DD + (size_t)ck*8*DD + n;
    union { u16 u[8]; uint4 v; } pk;
    #pragma unroll
    for (int e=0;e<8;e++) pk.u[e] = f2bf(src[(size_t)e*DD]);
    *(uint4*)(dWkT + (size_t)i*DD*DD + (size_t)n*DD + ck*8) = pk.v;
    return;
  }
  blk -= NB_TRAN;
  if (blk < NB_PREC) {
    int i = blk / 1025, row = blk % 1025;
    const float* W    = (i==0)?Wq_:(i==1)?Wk_:(i==2)?Wv_:Wo_;
    const float* bvec = (i==0)?bq_:(i==1)?bk_:(i==2)?bv_:bo_;
    const float* s = dWv + i*DD;
    __shared__ float red[256];
    float acc = 0.f;
    if (row < DD) {
      const float* r = W + (size_t)row * DD;
      for (int e = t; e < DD; e += 256) acc += r[e]*s[e];
    } else {
      for (int e = t; e < DD; e += 256) acc += bvec[e]*s[e];
    }
    red[t] = acc; __syncthreads();
    for (int off=128; off>0; off>>=1){ if(t<off) red[t]+=red[t+off]; __syncthreads(); }
    if (t==0) {
      if (row < DD) wv[i*DD + row] = red[0];
      else          cv[i] = red[0] + dbv[i];
    }
    return;
  }
  blk -= NB_PREC;
  {  // zero l/pv accumulators: 64 blocks x 256 thr x 8 floats = 131072
    size_t idx = ((size_t)blk*256 + t)*8;
    *(float4*)(lpv_zero + idx)     = make_float4(0.f,0.f,0.f,0.f);
    *(float4*)(lpv_zero + idx + 4) = make_float4(0.f,0.f,0.f,0.f);
  }
}

// ---------------------------------------------------------------------------
// Kernel 2: kraw[i] = x @ dWk[i], bf16 MFMA (m97 structure; unchanged).
__global__ __launch_bounds__(256) void gemm_dwk_mfma(const u16* __restrict__ xb,
                          const u16* __restrict__ Bt, u16* __restrict__ kraw) {
  const int i = blockIdx.z;
  const u16* Bm = Bt + (size_t)i*DD*DD;
  u16* C = kraw + (size_t)i*MM*DD;
  const int n0 = blockIdx.x*128, m0 = blockIdx.y*128;
  const int t = threadIdx.x, w = t>>6, lane = t&63;
  const int q15 = lane&15, quad = lane>>4;
  const int wm = w>>1, wn = w&1;
  const int lr = lane>>3, lc = lane&7, gsw = lc ^ lr;
  const int sw = q15 & 7;
  __shared__ u16 As[128*64];
  __shared__ u16 Bs[128*64];
  f32x4 acc[4][4];
  #pragma unroll
  for(int a=0;a<4;a++)
    #pragma unroll
    for(int b2=0;b2<4;b2++) acc[a][b2] = (f32x4){0.f,0.f,0.f,0.f};

  for (int k0=0; k0<DD; k0+=64) {
    __syncthreads();
    #pragma unroll
    for (int j=0; j<4; j++) {
      int r = (w*4+j)*8 + lr;
      gl_lds16(xb + (size_t)(m0+r)*DD + k0 + gsw*8, &As[((w*4+j)*8)*64]);
      gl_lds16(Bm + (size_t)(n0+r)*DD + k0 + gsw*8, &Bs[((w*4+j)*8)*64]);
    }
    __syncthreads();
    #pragma unroll
    for (int kk=0; kk<2; kk++) {
      bf16x8 af[4], bfr[4];
      #pragma unroll
      for (int mt=0; mt<4; mt++)
        af[mt]  = *(bf16x8*)(&As[(wm*64+mt*16+q15)*64 + ((kk*4+quad)^sw)*8]);
      #pragma unroll
      for (int nt=0; nt<4; nt++)
        bfr[nt] = *(bf16x8*)(&Bs[(wn*64+nt*16+q15)*64 + ((kk*4+quad)^sw)*8]);
      #pragma unroll
      for (int mt=0; mt<4; mt++)
        #pragma unroll
        for (int nt=0; nt<4; nt++)
          acc[mt][nt] = __builtin_amdgcn_mfma_f32_16x16x32_bf16(af[mt], bfr[nt], acc[mt][nt], 0,0,0);
    }
  }
  #pragma unroll
  for (int mt=0; mt<4; mt++)
    #pragma unroll
    for (int nt=0; nt<4; nt++)
      #pragma unroll
      for (int r=0; r<4; r++) {
        int m = m0 + wm*64 + mt*16 + quad*4 + r;
        int n = n0 + wn*64 + nt*16 + q15;
        C[(size_t)m*DD + n] = f2bf(acc[mt][nt][r]);
      }
}

// ---------------------------------------------------------------------------
// Kernel 3: delta i=0..2 -> q' (pre-scaled) + k planes bf16, Vw[b][h][s].
__global__ void delta_qkv_kernel(const float* __restrict__ x, const u16* __restrict__ kraw,
                                 const float* __restrict__ dbw, const float* __restrict__ dbb,
                                 const float* __restrict__ wv, const float* __restrict__ cv,
                                 u16* __restrict__ qk, float* __restrict__ Vw) {
  int m = blockIdx.x, t = threadIdx.x, w = t>>6, lane = t&63;
  const float* xr = x + (size_t)m*DD;
  float4 xv = *(const float4*)(xr + t*4);
  __shared__ float4 part[3][4];
  float4 kvs[3];
  #pragma unroll
  for (int i=0;i<3;i++) {
    ushort4 ku = *(const ushort4*)(kraw + (size_t)i*MM*DD + (size_t)m*DD + t*4);
    float4 kv = make_float4(bf2f(ku.x), bf2f(ku.y), bf2f(ku.z), bf2f(ku.w));
    kvs[i] = kv;
    float4 bwv = *(const float4*)(dbw + i*DD + t*4);
    float4 wvv = *(const float4*)(wv  + i*DD + t*4);
    float4 red = make_float4(dot4f(kv,kv), dot4f(kv,xv), dot4f(xv,bwv), dot4f(xv,wvv));
    #pragma unroll
    for (int off=32; off>0; off>>=1) {
      red.x += __shfl_xor(red.x, off);
      red.y += __shfl_xor(red.y, off);
      red.z += __shfl_xor(red.z, off);
      red.w += __shfl_xor(red.w, off);
    }
    if (lane==0) part[i][w] = red;
  }
  __syncthreads();
  float cc[3];
  #pragma unroll
  for (int i=0;i<3;i++) {
    float4 r0=part[i][0], r1=part[i][1], r2=part[i][2], r3=part[i][3];
    float s0=r0.x+r1.x+r2.x+r3.x, s1=r0.y+r1.y+r2.y+r3.y;
    float s2=r0.z+r1.z+r2.z+r3.z, s3=r0.w+r1.w+r2.w+r3.w;
    float nrmE = sqrtf(s0) + 1e-8f;
    float kdh  = s1 / nrmE;
    float beta = 2.f / (1.f + __expf(-(s2 + dbb[i])));
    float vs   = s3 + cv[i];
    cc[i] = beta * (vs - kdh) / nrmE;
  }
  {
    float c = cc[0]; float4 kv = kvs[0];
    ushort4 ou;
    ou.x = f2bf((xv.x + c*kv.x)*QSCALE); ou.y = f2bf((xv.y + c*kv.y)*QSCALE);
    ou.z = f2bf((xv.z + c*kv.z)*QSCALE); ou.w = f2bf((xv.w + c*kv.w)*QSCALE);
    *(ushort4*)(qk + (size_t)m*DD + t*4) = ou;
  }
  {
    float c = cc[1]; float4 kv = kvs[1];
    ushort4 ou;
    ou.x = f2bf(xv.x + c*kv.x); ou.y = f2bf(xv.y + c*kv.y);
    ou.z = f2bf(xv.z + c*kv.z); ou.w = f2bf(xv.w + c*kv.w);
    *(ushort4*)(qk + (size_t)MM*DD + (size_t)m*DD + t*4) = ou;
  }
  {
    float c = cc[2]; float4 kv = kvs[2];
    float4 vv = make_float4(xv.x + c*kv.x, xv.y + c*kv.y, xv.z + c*kv.z, xv.w + c*kv.w);
    float4 w3 = *(const float4*)(wv + 3*DD + t*4);
    float s = dot4f(vv, w3);
    #pragma unroll
    for (int off=1; off<16; off<<=1) s += __shfl_xor(s, off);
    if ((lane & 15) == 0) {
      int head = t >> 4;
      int b = m >> 11, srow = m & (SS-1);
      Vw[((size_t)(b*HH + head))*SS + srow] = s;
    }
  }
}

// ---------------------------------------------------------------------------
// Kernel 4: split-K QK^T flash. grid (32, 16, BB*KC), block 256.
// Double-buffered K via global_load_lds DMA; ONE barrier per kt; Vw in regs.
// Partial l / p.Vw accumulated, atomicAdd per (token,head).
__global__ __launch_bounds__(256) void flash_mfma(const u16* __restrict__ qb,
     const u16* __restrict__ kb, const float* __restrict__ Vw,
     float* __restrict__ l_arr, float* __restrict__ pv_arr) {
  const int qt = blockIdx.x, h = blockIdx.y;
  const int b = blockIdx.z >> 2, kc = blockIdx.z & 3;
  const int t = threadIdx.x, w = t>>6, lane = t&63, q15 = lane&15, quad = lane>>4;
  const int lr = lane>>3, lc = lane&7, gsw = lc ^ lr;
  const int sw = q15 & 7;
  __shared__ u16 Qs[64*64];
  __shared__ u16 Ks[2][64*64];
  const size_t hb = (size_t)h*HD;
  const u16* kbase = kb + (size_t)(b*SS + kc*KT_PER*64)*DD + hb;
  const float* vwb = Vw + (size_t)(b*HH + h)*SS + kc*KT_PER*64;

  // stage Q + K tile 0 via DMA
  #pragma unroll
  for (int j=0; j<2; j++) {
    int r = (w*2+j)*8 + lr;
    gl_lds16(qb + (size_t)(b*SS + qt*64 + r)*DD + hb + gsw*8, &Qs[((w*2+j)*8)*64]);
    gl_lds16(kbase + (size_t)r*DD + gsw*8, &Ks[0][((w*2+j)*8)*64]);
  }
  // Vw register prefetch for kt=0 (16 lanes same addr -> broadcast)
  float4 vwreg[4];
  #pragma unroll
  for (int rt=0; rt<4; rt++) vwreg[rt] = *(const float4*)(vwb + rt*16 + quad*4);

  float l_acc = 0.f, pv_acc = 0.f;
  __syncthreads();                              // Q + K0 staged
  bf16x8 qf[2];
  #pragma unroll
  for (int kk=0; kk<2; kk++)
    qf[kk] = *(bf16x8*)(&Qs[(w*16+q15)*64 + ((kk*4+quad)^sw)*8]);

  for (int kt=0; kt<KT_PER; kt++) {
    // DMA next K tile into the other buffer (overlaps this tile's compute)
    if (kt+1 < KT_PER) {
      #pragma unroll
      for (int j=0; j<2; j++) {
        int r = (w*2+j)*8 + lr;
        gl_lds16(kbase + (size_t)((kt+1)*64 + r)*DD + gsw*8,
                 &Ks[(kt+1)&1][((w*2+j)*8)*64]);
      }
    }
    // S^T: rows = keys (rt*16+quad*4+r), cols = q (w*16+q15)
    f32x4 Sacc[4];
    #pragma unroll
    for (int rt=0; rt<4; rt++) Sacc[rt] = (f32x4){0.f,0.f,0.f,0.f};
    #pragma unroll
    for (int kk=0; kk<2; kk++) {
      #pragma unroll
      for (int rt=0; rt<4; rt++) {
        bf16x8 kf = *(bf16x8*)(&Ks[kt&1][(rt*16+q15)*64 + ((kk*4+quad)^sw)*8]);
        Sacc[rt] = __builtin_amdgcn_mfma_f32_16x16x32_bf16(kf, qf[kk], Sacc[rt], 0,0,0);
      }
    }
    float4 vwcur[4];
    #pragma unroll
    for (int rt=0; rt<4; rt++) vwcur[rt] = vwreg[rt];
    if (kt+1 < KT_PER) {
      #pragma unroll
      for (int rt=0; rt<4; rt++)
        vwreg[rt] = *(const float4*)(vwb + (kt+1)*64 + rt*16 + quad*4);
    }
    #pragma unroll
    for (int rt=0; rt<4; rt++) {
      float va[4] = {vwcur[rt].x, vwcur[rt].y, vwcur[rt].z, vwcur[rt].w};
      #pragma unroll
      for (int r=0; r<4; r++) {
        float p = EXP2F(fminf(Sacc[rt][r], 30.f));
        l_acc  += p;
        pv_acc += p * va[r];
      }
    }
    __syncthreads();   // releases Ks[kt&1] for DMA overwrite; drains next DMA
  }
  // reduce across quads (lanes sharing q column q15)
  l_acc  += __shfl_xor(l_acc, 16);  l_acc  += __shfl_xor(l_acc, 32);
  pv_acc += __shfl_xor(pv_acc, 16); pv_acc += __shfl_xor(pv_acc, 32);
  if (quad == 0) {
    int tok = b*SS + qt*64 + w*16 + q15;
    atomicAdd(&l_arr[(size_t)tok*HH + h],  l_acc);
    atomicAdd(&pv_arr[(size_t)tok*HH + h], pv_acc);
  }
}

// ---------------------------------------------------------------------------
// Kernel 5: v3 = sum_h pv/l, delta #3 + LayerNorm. grid MM, block 256.
__global__ void final_kernel(const float* __restrict__ x, const u16* __restrict__ kraw3,
                             const float* __restrict__ l_arr, const float* __restrict__ pv_arr,
                             const float* __restrict__ dbw, const float* __restrict__ dbb,
                             const float* __restrict__ cv,
                             const float* __restrict__ ln_g, const float* __restrict__ ln_b,
                             float* __restrict__ out) {
  int m = blockIdx.x, t = threadIdx.x, w = t>>6, lane = t&63;
  const float* xr = x     + (size_t)m*DD;
  const u16*   kr = kraw3 + (size_t)m*DD;
  float4 xv  = *(const float4*)(xr + t*4);
  ushort4 ku = *(const ushort4*)(kr + t*4);
  float4 kv  = make_float4(bf2f(ku.x), bf2f(ku.y), bf2f(ku.z), bf2f(ku.w));
  float4 bwv = *(const float4*)(dbw + 3*DD + t*4);
  __shared__ float4 part[4];
  __shared__ float2 part2[4];
  __shared__ float v3s;
  if (t < 16) {
    float val = pv_arr[(size_t)m*HH + t] / l_arr[(size_t)m*HH + t];
    #pragma unroll
    for (int off=1; off<16; off<<=1) val += __shfl_xor(val, off);
    if (t==0) v3s = val;
  }
  float4 red = make_float4(dot4f(kv,kv), dot4f(kv,xv), dot4f(xv,bwv), 0.f);
  #pragma unroll
  for (int off=32; off>0; off>>=1) {
    red.x += __shfl_xor(red.x, off);
    red.y += __shfl_xor(red.y, off);
    red.z += __shfl_xor(red.z, off);
  }
  if (lane==0) part[w] = red;
  __syncthreads();
  float4 r0=part[0], r1=part[1], r2=part[2], r3=part[3];
  float s0=r0.x+r1.x+r2.x+r3.x, s1=r0.y+r1.y+r2.y+r3.y, s2=r0.z+r1.z+r2.z+r3.z;
  float nrmE = sqrtf(s0) + 1e-8f;
  float kdh  = s1 / nrmE;
  float beta = 2.f / (1.f + __expf(-(s2 + dbb[3])));
  float v3   = v3s + cv[3];
  float c = beta * (v3 - kdh) / nrmE;
  float y0 = xv.x + c*kv.x, y1 = xv.y + c*kv.y, y2 = xv.z + c*kv.z, y3 = xv.w + c*kv.w;
  float2 rr = make_float2(y0+y1+y2+y3, y0*y0+y1*y1+y2*y2+y3*y3);
  #pragma unroll
  for (int off=32; off>0; off>>=1) {
    rr.x += __shfl_xor(rr.x, off);
    rr.y += __shfl_xor(rr.y, off);
  }
  if (lane==0) part2[w] = rr;
  __syncthreads();
  float ssum = part2[0].x+part2[1].x+part2[2].x+part2[3].x;
  float ssq  = part2[0].y+part2[1].y+part2[2].y+part2[3].y;
  float mu   = ssum * (1.f/DD);
  float var  = ssq * (1.f/DD) - mu*mu;
  float rstd = rsqrtf(var + 1e-5f);
  float4 g  = *(const float4*)(ln_g + t*4);
  float4 bb = *(const float4*)(ln_b + t*4);
  float4 ov;
  ov.x = (y0-mu)*rstd*g.x + bb.x;
  ov.y = (y1-mu)*rstd*g.y + bb.y;
  ov.z = (y2-mu)*rstd*g.z + bb.z;
  ov.w = (y3-mu)*rstd*g.w + bb.w;
  *(float4*)(out + (size_t)m*DD + t*4) = ov;
}

// ---------------------------------------------------------------------------
extern "C" void kernel_launch(void* const* d_in, const int* in_sizes, int n_in,
                              void* d_out, int out_size, void* d_ws, size_t ws_size,
                              hipStream_t stream) {
  const float* x    = (const float*)d_in[0];
  const float* Wq_  = (const float*)d_in[1];
  const float* bq_  = (const float*)d_in[2];
  const float* Wk_  = (const float*)d_in[3];
  const float* bk_  = (const float*)d_in[4];
  const float* Wv_  = (const float*)d_in[5];
  const float* bv_  = (const float*)d_in[6];
  const float* Wo_  = (const float*)d_in[7];
  const float* bo_  = (const float*)d_in[8];
  const float* dWk  = (const float*)d_in[9];
  const float* dbw  = (const float*)d_in[10];
  const float* dbb  = (const float*)d_in[11];
  const float* dWv  = (const float*)d_in[12];
  const float* dbv  = (const float*)d_in[13];
  const float* ln_g = (const float*)d_in[14];
  const float* ln_b = (const float*)d_in[15];
  float* out = (float*)d_out;
  char* WS = (char*)d_ws;

  // workspace layout (bytes):
  float* wv     = (float*)WS;                                 // 16 KB
  float* cv     = (float*)(WS + 16384);                       // 256 B
  u16*   kraw   = (u16*)  (WS + 16640);                       // 4*MM*DD bf16 = 33.5 MB
  u16*   qk     = (u16*)  (WS + 16640 + (size_t)4*MM*DD*2);   // 2*MM*DD bf16 = 16.8 MB
  u16*   dWkT   = (u16*)  (WS + 16640 + (size_t)6*MM*DD*2);   // 8.4 MB
  u16*   xb     = (u16*)  (WS + 16640 + (size_t)6*MM*DD*2 + (size_t)4*DD*DD*2); // 8.4 MB
  char*  tail   = WS + 16640 + (size_t)6*MM*DD*2 + (size_t)8*DD*DD*2;
  float* Vw     = (float*)tail;                               // BB*HH*SS f32 = 256 KB
  float* l_arr  = (float*)(tail + (size_t)BB*HH*SS*4);        // MM*HH f32 = 256 KB
  float* pv_arr = (float*)(tail + (size_t)BB*HH*SS*4 + (size_t)MM*HH*4); // 256 KB

  prep_kernel<<<NB_CONV+NB_TRAN+NB_PREC+NB_ZERO, 256, 0, stream>>>(
      x, xb, dWk, dWkT, Wq_,bq_,Wk_,bk_,Wv_,bv_,Wo_,bo_, dWv, dbv, wv, cv, l_arr);
  gemm_dwk_mfma<<<dim3(8, 32, 4), 256, 0, stream>>>(xb, dWkT, kraw);
  delta_qkv_kernel<<<MM, 256, 0, stream>>>(x, kraw, dbw, dbb, wv, cv, qk, Vw);
  flash_mfma<<<dim3(SS/64, HH, BB*KC), 256, 0, stream>>>(
      qk, qk + (size_t)MM*DD, Vw, l_arr, pv_arr);
  final_kernel<<<MM, 256, 0, stream>>>(x, kraw + 3*(size_t)MM*DD, l_arr, pv_arr,
                                       dbw, dbb, cv, ln_g, ln_b, out);
}